// Round 9
// baseline (163.133 us; speedup 1.0000x reference)
//
#include <hip/hip_runtime.h>
#include <stdint.h>

#define SEQ 4096
#define DM 768
#define NH 12
#define HD 64

typedef __attribute__((ext_vector_type(8))) short bf8;
typedef __attribute__((ext_vector_type(4))) float f4;
typedef __attribute__((ext_vector_type(16))) float f32x16;

static __device__ __forceinline__ f4 mfma_bf16(bf8 a, bf8 b, f4 c) {
  return __builtin_amdgcn_mfma_f32_16x16x32_bf16(a, b, c, 0, 0, 0);
}
static __device__ __forceinline__ f32x16 mfma32(bf8 a, bf8 b, f32x16 c) {
  return __builtin_amdgcn_mfma_f32_32x32x16_bf16(a, b, c, 0, 0, 0);
}

// RNE float->bf16 (bit pattern)
static __device__ __forceinline__ unsigned short f2bf(float f) {
  unsigned int u = __float_as_uint(f);
  u += 0x7FFFu + ((u >> 16) & 1u);
  return (unsigned short)(u >> 16);
}

// packed f32 pair -> bf16 pair (lo in low 16, hi in high 16)
static __device__ __forceinline__ unsigned int cvtpk(float lo, float hi) {
  unsigned int r;
  asm("v_cvt_pk_bf16_f32 %0, %1, %2" : "=v"(r) : "v"(lo), "v"(hi));
  return r;
}

static __device__ __forceinline__ void gload_lds16(const void* g, void* l) {
  __builtin_amdgcn_global_load_lds(
      (const __attribute__((address_space(1))) void*)g,
      (__attribute__((address_space(3))) void*)l, 16, 0, 0);
}

// ---- cast x (fp32) -> bf16 -----------------------------------------------
__global__ __launch_bounds__(256) void k_cvt(const float* __restrict__ x,
                                             unsigned short* __restrict__ xb) {
  int i = (blockIdx.x * 256 + threadIdx.x) * 4;
  float4 v = *reinterpret_cast<const float4*>(x + i);
  ushort4 o;
  o.x = f2bf(v.x); o.y = f2bf(v.y); o.z = f2bf(v.z); o.w = f2bf(v.w);
  *reinterpret_cast<ushort4*>(xb + i) = o;
}

// ---- transpose+cast weights: WT[z][n][k] = bf16(W[k][n]) -----------------
__global__ __launch_bounds__(256) void k_tw(const float* __restrict__ w0,
                                            const float* __restrict__ w1,
                                            const float* __restrict__ w2,
                                            const float* __restrict__ w3,
                                            unsigned short* __restrict__ wt) {
  const float* W = blockIdx.z == 0 ? w0 : blockIdx.z == 1 ? w1
                 : blockIdx.z == 2 ? w2 : w3;
  unsigned short* WT = wt + (size_t)blockIdx.z * DM * DM;
  __shared__ float t[32][33];
  int c0 = blockIdx.x * 32, r0 = blockIdx.y * 32;
  int lx = threadIdx.x & 31, ly = threadIdx.x >> 5;
#pragma unroll
  for (int rr = 0; rr < 32; rr += 8)
    t[ly + rr][lx] = W[(size_t)(r0 + ly + rr) * DM + c0 + lx];
  __syncthreads();
#pragma unroll
  for (int rr = 0; rr < 32; rr += 8)
    WT[(size_t)(c0 + ly + rr) * DM + r0 + lx] = f2bf(t[lx][ly + rr]);
}

// ---- bf16 MFMA GEMM: C[4096][768] = A[4096][768] @ Bt[768][768]^T --------
// MODE 0: store bf16 [row][768] * scale   (Q gets softmax scale folded in)
// MODE 1: store bf16 transposed Vt[col][4096]
// MODE 2: store fp32 [row][768] + bias[col]
template <int MODE>
__global__ __launch_bounds__(256) void k_gemm(const unsigned short* __restrict__ A,
                                              const unsigned short* __restrict__ Bt,
                                              void* __restrict__ Cout,
                                              const float* __restrict__ bias,
                                              float scale) {
  constexpr int K = DM;
  __shared__ unsigned short sA[128 * 32];
  __shared__ unsigned short sB[64 * 32];
  const int t = threadIdx.x, lane = t & 63, w = t >> 6;
  const int wr = w >> 1, wc = w & 1;
  const int c = lane & 15, g = lane >> 4;
  const int brow = blockIdx.x * 128, bcol = blockIdx.y * 64;
  f4 acc[4][2] = {};
  for (int k0 = 0; k0 < K; k0 += 32) {
#pragma unroll
    for (int i = 0; i < 2; ++i) {
      int slot = w * 2 + i;
      int chunk = slot * 64 + lane;
      int row = chunk >> 2;
      int sl = (chunk & 3) ^ ((row >> 1) & 3);
      gload_lds16(A + (size_t)(brow + row) * K + k0 + sl * 8, &sA[slot * 512]);
    }
    {
      int chunk = w * 64 + lane;
      int row = chunk >> 2;
      int sl = (chunk & 3) ^ ((row >> 1) & 3);
      gload_lds16(Bt + (size_t)(bcol + row) * K + k0 + sl * 8, &sB[w * 512]);
    }
    __syncthreads();
    bf8 af[4], bfr[2];
#pragma unroll
    for (int m = 0; m < 4; ++m) {
      int row = wr * 64 + m * 16 + c;
      int off = row * 64 + ((g * 16) ^ (((row >> 1) & 3) << 4));
      af[m] = *reinterpret_cast<const bf8*>(reinterpret_cast<const char*>(sA) + off);
    }
#pragma unroll
    for (int n = 0; n < 2; ++n) {
      int row = wc * 32 + n * 16 + c;
      int off = row * 64 + ((g * 16) ^ (((row >> 1) & 3) << 4));
      bfr[n] = *reinterpret_cast<const bf8*>(reinterpret_cast<const char*>(sB) + off);
    }
#pragma unroll
    for (int m = 0; m < 4; ++m)
#pragma unroll
      for (int n = 0; n < 2; ++n)
        acc[m][n] = mfma_bf16(af[m], bfr[n], acc[m][n]);
    __syncthreads();
  }
#pragma unroll
  for (int m = 0; m < 4; ++m) {
#pragma unroll
    for (int n = 0; n < 2; ++n) {
      int col = bcol + wc * 32 + n * 16 + c;
      int row0 = brow + wr * 64 + m * 16 + g * 4;
      if (MODE == 0) {
        unsigned short* C = (unsigned short*)Cout;
#pragma unroll
        for (int r = 0; r < 4; ++r)
          C[(size_t)(row0 + r) * DM + col] = f2bf(acc[m][n][r] * scale);
      } else if (MODE == 1) {
        unsigned short* C = (unsigned short*)Cout;
        ushort4 p;
        p.x = f2bf(acc[m][n][0]); p.y = f2bf(acc[m][n][1]);
        p.z = f2bf(acc[m][n][2]); p.w = f2bf(acc[m][n][3]);
        *reinterpret_cast<ushort4*>(C + (size_t)col * SEQ + row0) = p;
      } else {
        float* C = (float*)Cout;
#pragma unroll
        for (int r = 0; r < 4; ++r)
          C[(size_t)(row0 + r) * DM + col] = acc[m][n][r] + bias[col];
      }
    }
  }
}

// ---- attention helpers ----------------------------------------------------
// Volatile asm loads: cannot be sunk by the compiler; "=v" keeps the
// destination registers allocated from issue to use (true prefetch).
#define ALOADK(kf, addr) do {                                                 \
    asm volatile("global_load_dwordx4 %0, %1, off"           : "=v"(kf[0]) : "v"(addr)); \
    asm volatile("global_load_dwordx4 %0, %1, off offset:32" : "=v"(kf[1]) : "v"(addr)); \
    asm volatile("global_load_dwordx4 %0, %1, off offset:64" : "=v"(kf[2]) : "v"(addr)); \
    asm volatile("global_load_dwordx4 %0, %1, off offset:96" : "=v"(kf[3]) : "v"(addr)); \
  } while (0)

#define ALOADV(vf, a0, a1) do {                                               \
    asm volatile("global_load_dwordx4 %0, %1, off"           : "=v"(vf[0]) : "v"(a0)); \
    asm volatile("global_load_dwordx4 %0, %1, off offset:32" : "=v"(vf[1]) : "v"(a0)); \
    asm volatile("global_load_dwordx4 %0, %1, off"           : "=v"(vf[2]) : "v"(a1)); \
    asm volatile("global_load_dwordx4 %0, %1, off offset:32" : "=v"(vf[3]) : "v"(a1)); \
  } while (0)

#define PSWAP(a, b) asm volatile("v_permlane32_swap_b32 %0, %1" : "+v"(a), "+v"(b))

// Counted-vmcnt step: wait WK (K-frags ready) before QK; wait WV (V-frags
// ready) before PV. sched_barrier(0) fences MFMA hoisting past the waits
// (rule #18). Never drains to 0 in steady state.
#define STEPW(kf, vf, t, WK, WV) do {                                         \
    asm volatile("s_waitcnt vmcnt(" #WK ")");                                 \
    __builtin_amdgcn_sched_barrier(0);                                        \
    f32x16 s_ = {};                                                           \
    __builtin_amdgcn_s_setprio(1);                                            \
    s_ = mfma32(kf[0], qf[0], s_);                                            \
    s_ = mfma32(kf[1], qf[1], s_);                                            \
    s_ = mfma32(kf[2], qf[2], s_);                                            \
    s_ = mfma32(kf[3], qf[3], s_);                                            \
    __builtin_amdgcn_s_setprio(0);                                            \
    if ((t) == qt) {                                                          \
      _Pragma("unroll")                                                       \
      for (int r_ = 0; r_ < 16; ++r_) {                                       \
        int kr_ = (t) * 32 + (r_ & 3) + 8 * (r_ >> 2) + 4 * hi;               \
        s_[r_] = (kr_ > qg) ? -1e30f : s_[r_];                                \
      }                                                                       \
    }                                                                         \
    float tm_ = fmaxf(fmaxf(fmaxf(fmaxf(s_[0], s_[1]), fmaxf(s_[2], s_[3])), \
                            fmaxf(fmaxf(s_[4], s_[5]), fmaxf(s_[6], s_[7]))),\
                      fmaxf(fmaxf(fmaxf(s_[8], s_[9]), fmaxf(s_[10], s_[11])),\
                            fmaxf(fmaxf(s_[12], s_[13]), fmaxf(s_[14], s_[15]))));\
    tm_ = fmaxf(tm_, __shfl_xor(tm_, 32));                                    \
    float mn_ = fmaxf(m, tm_);                                                \
    float al_ = __builtin_amdgcn_exp2f(m - mn_);                              \
    m = mn_;                                                                  \
    float p0_ = __builtin_amdgcn_exp2f(s_[0] - mn_);                          \
    float p1_ = __builtin_amdgcn_exp2f(s_[1] - mn_);                          \
    float p2_ = __builtin_amdgcn_exp2f(s_[2] - mn_);                          \
    float p3_ = __builtin_amdgcn_exp2f(s_[3] - mn_);                          \
    float p4_ = __builtin_amdgcn_exp2f(s_[4] - mn_);                          \
    float p5_ = __builtin_amdgcn_exp2f(s_[5] - mn_);                          \
    float p6_ = __builtin_amdgcn_exp2f(s_[6] - mn_);                          \
    float p7_ = __builtin_amdgcn_exp2f(s_[7] - mn_);                          \
    unsigned int wa0_ = cvtpk(p0_, p1_), wa1_ = cvtpk(p2_, p3_);              \
    unsigned int wb0_ = cvtpk(p4_, p5_), wb1_ = cvtpk(p6_, p7_);              \
    float ls_ = ((p0_ + p1_) + (p2_ + p3_)) + ((p4_ + p5_) + (p6_ + p7_));    \
    float q0_ = __builtin_amdgcn_exp2f(s_[8] - mn_);                          \
    float q1_ = __builtin_amdgcn_exp2f(s_[9] - mn_);                          \
    float q2_ = __builtin_amdgcn_exp2f(s_[10] - mn_);                         \
    float q3_ = __builtin_amdgcn_exp2f(s_[11] - mn_);                         \
    float q4_ = __builtin_amdgcn_exp2f(s_[12] - mn_);                         \
    float q5_ = __builtin_amdgcn_exp2f(s_[13] - mn_);                         \
    float q6_ = __builtin_amdgcn_exp2f(s_[14] - mn_);                         \
    float q7_ = __builtin_amdgcn_exp2f(s_[15] - mn_);                         \
    unsigned int wc0_ = cvtpk(q0_, q1_), wc1_ = cvtpk(q2_, q3_);              \
    unsigned int wd0_ = cvtpk(q4_, q5_), wd1_ = cvtpk(q6_, q7_);              \
    ls_ += ((q0_ + q1_) + (q2_ + q3_)) + ((q4_ + q5_) + (q6_ + q7_));         \
    PSWAP(wa0_, wb0_);                                                        \
    PSWAP(wa1_, wb1_);                                                        \
    PSWAP(wc0_, wd0_);                                                        \
    PSWAP(wc1_, wd1_);                                                        \
    ls_ += __shfl_xor(ls_, 32);                                               \
    l = l * al_ + ls_;                                                        \
    _Pragma("unroll")                                                         \
    for (int r_ = 0; r_ < 16; ++r_) { o0[r_] *= al_; o1[r_] *= al_; }         \
    uint4 u0_ = {wa0_, wa1_, wb0_, wb1_};                                     \
    uint4 u1_ = {wc0_, wc1_, wd0_, wd1_};                                     \
    bf8 pf0_ = *reinterpret_cast<bf8*>(&u0_);                                 \
    bf8 pf1_ = *reinterpret_cast<bf8*>(&u1_);                                 \
    asm volatile("s_waitcnt vmcnt(" #WV ")");                                 \
    __builtin_amdgcn_sched_barrier(0);                                        \
    __builtin_amdgcn_s_setprio(1);                                            \
    o0 = mfma32(vf[0], pf0_, o0);                                             \
    o0 = mfma32(vf[1], pf1_, o0);                                             \
    o1 = mfma32(vf[2], pf0_, o1);                                             \
    o1 = mfma32(vf[3], pf1_, o1);                                             \
    __builtin_amdgcn_s_setprio(0);                                            \
  } while (0)

// ---- causal flash attention: paired q-tiles + split-K x4 + XCD chunking --
// Block = 4 waves, q-tiles {b, 127-b} -> uniform 129 tiles/block, 768
// blocks = exactly 3/CU. XCD chunk: W=(L&7)*96+(L>>3) -> 1.5 heads/XCD
// (K+V L2-resident; R6: FETCH 10.8MB). K and V register-double-buffered
// via volatile-asm global_load_dwordx4 + counted vmcnt (async pipeline
// the compiler cannot undo). K over-issues <=tile 131 (lands in the Vt
// region of d_ws; loaded-but-unused, memory-safe).
__global__ __launch_bounds__(256, 3) void k_attn(const unsigned short* __restrict__ Qb,
                                                 const unsigned short* __restrict__ Kb,
                                                 const unsigned short* __restrict__ Vt,
                                                 unsigned short* __restrict__ ctx) {
  const int tid = threadIdx.x;
  const int lane = tid & 63;
  const int w = tid >> 6;  // split-K wave index, 0..3
  const int ql = lane & 31, hi = lane >> 5;

  const int L = (int)blockIdx.x;          // 0..767
  const int W = (L & 7) * 96 + (L >> 3);  // XCD-chunked work id
  const int h = W >> 6;
  const int b = W & 63;
  const size_t hd = (size_t)h * HD;

  __shared__ float sO[4][64][32];
  __shared__ float sM[4][32];
  __shared__ float sL[4][32];

  const uint64_t TKB = (uint64_t)32 * DM * 2;  // K-tile stride in bytes
  const uint64_t Kb0 = (uint64_t)(Kb + (size_t)ql * DM + hd + hi * 8);
  const uint64_t Vb0 = (uint64_t)(Vt + (hd + ql) * SEQ + hi * 8);

  for (int ph = 0; ph < 2; ++ph) {
    const int qt = ph ? (127 - b) : b;
    const int qg = qt * 32 + ql;
    // Q as B-fragments: col=q=lane&31, k(d)=8*hi+j
    bf8 qf[4];
    {
      const unsigned short* qp = Qb + (size_t)qg * DM + hd + hi * 8;
      qf[0] = *reinterpret_cast<const bf8*>(qp);
      qf[1] = *reinterpret_cast<const bf8*>(qp + 16);
      qf[2] = *reinterpret_cast<const bf8*>(qp + 32);
      qf[3] = *reinterpret_cast<const bf8*>(qp + 48);
    }
    f32x16 o0 = {}, o1 = {};
    float m = -1e30f, l = 0.f;

    const int nt = (qt >= w) ? ((qt - w) >> 2) + 1 : 0;
    bf8 kA[4], kB[4], vA[4], vB[4];
    uint64_t ka = Kb0 + (uint64_t)w * TKB;
    uint64_t kb2 = ka + 4 * TKB;
    uint64_t va = Vb0 + (uint64_t)w * 64;
    uint64_t va2 = va + (uint64_t)32 * SEQ * 2;
    uint64_t vb = va + 4 * 64;
    uint64_t vb2 = va2 + 4 * 64;

    if (nt > 0) { ALOADK(kA, ka); ka += 8 * TKB; }
    int i = 0;
    for (; i + 2 <= nt; i += 2) {
      const int tA_ = w + 4 * i, tB_ = tA_ + 4;
      ALOADV(vA, va, va2); va += 512; va2 += 512;
      ALOADK(kB, kb2); kb2 += 8 * TKB;
      STEPW(kA, vA, tA_, 8, 4);
      ALOADV(vB, vb, vb2); vb += 512; vb2 += 512;
      ALOADK(kA, ka); ka += 8 * TKB;  // unconditional (may over-read, see above)
      STEPW(kB, vB, tB_, 8, 4);
    }
    if (i < nt) {
      const int tA_ = w + 4 * i;
      ALOADV(vA, va, va2);
      STEPW(kA, vA, tA_, 4, 0);
    }
    asm volatile("s_waitcnt vmcnt(0)");  // drain over-issued loads

    // ---- 4-way split-K merge via LDS ----
#pragma unroll
    for (int r = 0; r < 16; ++r) {
      int dr = (r & 3) + 8 * (r >> 2) + 4 * hi;
      sO[w][dr][ql] = o0[r];
      sO[w][32 + dr][ql] = o1[r];
    }
    if (hi == 0) { sM[w][ql] = m; sL[w][ql] = l; }
    __syncthreads();
    {
      const int q = tid & 31;
      const int dblk = tid >> 5;  // 0..7, 8 d-values each
      float m0 = sM[0][q], m1 = sM[1][q], m2 = sM[2][q], m3 = sM[3][q];
      float mn = fmaxf(fmaxf(m0, m1), fmaxf(m2, m3));
      float a0 = __builtin_amdgcn_exp2f(m0 - mn);
      float a1 = __builtin_amdgcn_exp2f(m1 - mn);
      float a2 = __builtin_amdgcn_exp2f(m2 - mn);
      float a3 = __builtin_amdgcn_exp2f(m3 - mn);
      float inv = 1.f / (a0 * sL[0][q] + a1 * sL[1][q] + a2 * sL[2][q] + a3 * sL[3][q]);
      a0 *= inv; a1 *= inv; a2 *= inv; a3 *= inv;
      unsigned short* cp = ctx + (size_t)(qt * 32 + q) * DM + hd + dblk * 8;
#pragma unroll
      for (int j = 0; j < 8; j += 2) {
        int d = dblk * 8 + j;
        float v0 = sO[0][d][q] * a0 + sO[1][d][q] * a1 + sO[2][d][q] * a2 + sO[3][d][q] * a3;
        float v1 = sO[0][d + 1][q] * a0 + sO[1][d + 1][q] * a1 + sO[2][d + 1][q] * a2 + sO[3][d + 1][q] * a3;
        *reinterpret_cast<unsigned int*>(cp + j) = cvtpk(v0, v1);
      }
    }
    __syncthreads();
  }
}

extern "C" void kernel_launch(void* const* d_in, const int* in_sizes, int n_in,
                              void* d_out, int out_size, void* d_ws, size_t ws_size,
                              hipStream_t stream) {
  const float* x  = (const float*)d_in[0];
  const float* Wq = (const float*)d_in[1];
  const float* Wk = (const float*)d_in[2];
  const float* Wv = (const float*)d_in[3];
  const float* Wo = (const float*)d_in[4];
  const float* bo = (const float*)d_in[5];

  unsigned short* xb = (unsigned short*)d_ws;
  unsigned short* wt = xb + (size_t)SEQ * DM;
  unsigned short* Qb = wt + (size_t)4 * DM * DM;
  unsigned short* Kb = Qb + (size_t)SEQ * DM;
  unsigned short* Vt = Kb + (size_t)SEQ * DM;
  unsigned short* cx = Vt + (size_t)SEQ * DM;

  const float qscale = 1.4426950408889634f / 8.0f;  // log2(e)/sqrt(HD)

  k_cvt<<<(SEQ * DM) / 1024, 256, 0, stream>>>(x, xb);
  k_tw<<<dim3(24, 24, 4), 256, 0, stream>>>(Wq, Wk, Wv, Wo, wt);
  dim3 gg(SEQ / 128, DM / 64);
  k_gemm<0><<<gg, 256, 0, stream>>>(xb, wt, Qb, nullptr, qscale);
  k_gemm<0><<<gg, 256, 0, stream>>>(xb, wt + (size_t)DM * DM, Kb, nullptr, 1.0f);
  k_gemm<1><<<gg, 256, 0, stream>>>(xb, wt + (size_t)2 * DM * DM, Vt, nullptr, 1.0f);
  k_attn<<<dim3(768), 256, 0, stream>>>(Qb, Kb, Vt, cx);
  k_gemm<2><<<gg, 256, 0, stream>>>(cx, wt + (size_t)3 * DM * DM, d_out, bo, 1.0f);
}

// Round 10
// 135.746 us; speedup vs baseline: 1.2018x; 1.2018x over previous
//
#include <hip/hip_runtime.h>
#include <stdint.h>

#define SEQ 4096
#define DM 768
#define NH 12
#define HD 64

typedef __attribute__((ext_vector_type(8))) short bf8;
typedef __attribute__((ext_vector_type(4))) float f4;
typedef __attribute__((ext_vector_type(16))) float f32x16;

static __device__ __forceinline__ f4 mfma_bf16(bf8 a, bf8 b, f4 c) {
  return __builtin_amdgcn_mfma_f32_16x16x32_bf16(a, b, c, 0, 0, 0);
}
static __device__ __forceinline__ f32x16 mfma32(bf8 a, bf8 b, f32x16 c) {
  return __builtin_amdgcn_mfma_f32_32x32x16_bf16(a, b, c, 0, 0, 0);
}

// RNE float->bf16 (bit pattern)
static __device__ __forceinline__ unsigned short f2bf(float f) {
  unsigned int u = __float_as_uint(f);
  u += 0x7FFFu + ((u >> 16) & 1u);
  return (unsigned short)(u >> 16);
}

// packed f32 pair -> bf16 pair (lo in low 16, hi in high 16)
static __device__ __forceinline__ unsigned int cvtpk(float lo, float hi) {
  unsigned int r;
  asm("v_cvt_pk_bf16_f32 %0, %1, %2" : "=v"(r) : "v"(lo), "v"(hi));
  return r;
}

static __device__ __forceinline__ void gload_lds16(const void* g, void* l) {
  __builtin_amdgcn_global_load_lds(
      (const __attribute__((address_space(1))) void*)g,
      (__attribute__((address_space(3))) void*)l, 16, 0, 0);
}

// ---- cast x (fp32) -> bf16 -----------------------------------------------
__global__ __launch_bounds__(256) void k_cvt(const float* __restrict__ x,
                                             unsigned short* __restrict__ xb) {
  int i = (blockIdx.x * 256 + threadIdx.x) * 4;
  float4 v = *reinterpret_cast<const float4*>(x + i);
  ushort4 o;
  o.x = f2bf(v.x); o.y = f2bf(v.y); o.z = f2bf(v.z); o.w = f2bf(v.w);
  *reinterpret_cast<ushort4*>(xb + i) = o;
}

// ---- transpose+cast weights: WT[z][n][k] = bf16(W[k][n]) -----------------
__global__ __launch_bounds__(256) void k_tw(const float* __restrict__ w0,
                                            const float* __restrict__ w1,
                                            const float* __restrict__ w2,
                                            const float* __restrict__ w3,
                                            unsigned short* __restrict__ wt) {
  const float* W = blockIdx.z == 0 ? w0 : blockIdx.z == 1 ? w1
                 : blockIdx.z == 2 ? w2 : w3;
  unsigned short* WT = wt + (size_t)blockIdx.z * DM * DM;
  __shared__ float t[32][33];
  int c0 = blockIdx.x * 32, r0 = blockIdx.y * 32;
  int lx = threadIdx.x & 31, ly = threadIdx.x >> 5;
#pragma unroll
  for (int rr = 0; rr < 32; rr += 8)
    t[ly + rr][lx] = W[(size_t)(r0 + ly + rr) * DM + c0 + lx];
  __syncthreads();
#pragma unroll
  for (int rr = 0; rr < 32; rr += 8)
    WT[(size_t)(c0 + ly + rr) * DM + r0 + lx] = f2bf(t[lx][ly + rr]);
}

// ---- bf16 MFMA GEMM: C[4096][768] = A[4096][768] @ Bt[768][768]^T --------
// MODE 0: store bf16 PER-HEAD [h][s][64] * scale   (Q/K; contiguous 128B rows)
// MODE 1: store bf16 transposed Vt[col][4096]
// MODE 2: store fp32 [row][768] + bias[col]
template <int MODE>
__global__ __launch_bounds__(256) void k_gemm(const unsigned short* __restrict__ A,
                                              const unsigned short* __restrict__ Bt,
                                              void* __restrict__ Cout,
                                              const float* __restrict__ bias,
                                              float scale) {
  constexpr int K = DM;
  __shared__ unsigned short sA[128 * 32];
  __shared__ unsigned short sB[64 * 32];
  const int t = threadIdx.x, lane = t & 63, w = t >> 6;
  const int wr = w >> 1, wc = w & 1;
  const int c = lane & 15, g = lane >> 4;
  const int brow = blockIdx.x * 128, bcol = blockIdx.y * 64;
  f4 acc[4][2] = {};
  for (int k0 = 0; k0 < K; k0 += 32) {
#pragma unroll
    for (int i = 0; i < 2; ++i) {
      int slot = w * 2 + i;
      int chunk = slot * 64 + lane;
      int row = chunk >> 2;
      int sl = (chunk & 3) ^ ((row >> 1) & 3);
      gload_lds16(A + (size_t)(brow + row) * K + k0 + sl * 8, &sA[slot * 512]);
    }
    {
      int chunk = w * 64 + lane;
      int row = chunk >> 2;
      int sl = (chunk & 3) ^ ((row >> 1) & 3);
      gload_lds16(Bt + (size_t)(bcol + row) * K + k0 + sl * 8, &sB[w * 512]);
    }
    __syncthreads();
    bf8 af[4], bfr[2];
#pragma unroll
    for (int m = 0; m < 4; ++m) {
      int row = wr * 64 + m * 16 + c;
      int off = row * 64 + ((g * 16) ^ (((row >> 1) & 3) << 4));
      af[m] = *reinterpret_cast<const bf8*>(reinterpret_cast<const char*>(sA) + off);
    }
#pragma unroll
    for (int n = 0; n < 2; ++n) {
      int row = wc * 32 + n * 16 + c;
      int off = row * 64 + ((g * 16) ^ (((row >> 1) & 3) << 4));
      bfr[n] = *reinterpret_cast<const bf8*>(reinterpret_cast<const char*>(sB) + off);
    }
#pragma unroll
    for (int m = 0; m < 4; ++m)
#pragma unroll
      for (int n = 0; n < 2; ++n)
        acc[m][n] = mfma_bf16(af[m], bfr[n], acc[m][n]);
    __syncthreads();
  }
#pragma unroll
  for (int m = 0; m < 4; ++m) {
#pragma unroll
    for (int n = 0; n < 2; ++n) {
      int col = bcol + wc * 32 + n * 16 + c;
      int row0 = brow + wr * 64 + m * 16 + g * 4;
      if (MODE == 0) {
        unsigned short* C = (unsigned short*)Cout;
        int h = col >> 6, d = col & 63;
#pragma unroll
        for (int r = 0; r < 4; ++r)
          C[((size_t)h * SEQ + row0 + r) * 64 + d] = f2bf(acc[m][n][r] * scale);
      } else if (MODE == 1) {
        unsigned short* C = (unsigned short*)Cout;
        ushort4 p;
        p.x = f2bf(acc[m][n][0]); p.y = f2bf(acc[m][n][1]);
        p.z = f2bf(acc[m][n][2]); p.w = f2bf(acc[m][n][3]);
        *reinterpret_cast<ushort4*>(C + (size_t)col * SEQ + row0) = p;
      } else {
        float* C = (float*)Cout;
#pragma unroll
        for (int r = 0; r < 4; ++r)
          C[(size_t)(row0 + r) * DM + col] = acc[m][n][r] + bias[col];
      }
    }
  }
}

// ---- attention helpers ----------------------------------------------------
#define PSWAP(a, b) asm volatile("v_permlane32_swap_b32 %0, %1" : "+v"(a), "+v"(b))

// Stage 64-row K tile (8KB, contiguous in Kh) into this wave's LDS buffer.
// Global source is pre-swizzled (chunk ^= row&7) so linear LDS + swizzled
// ds_read is conflict-reduced (rule #21: both-sides-or-neither).
#define STAGEK(tile) do {                                                     \
    const unsigned short* ks_ = Khp + (size_t)(tile) * 4096 + kLaneOff;       \
    _Pragma("unroll")                                                         \
    for (int j_ = 0; j_ < 8; ++j_)                                            \
      gload_lds16(ks_ + j_ * 512, kbuf + j_ * 1024);                          \
  } while (0)

// Issue 8 V fragment loads (volatile: cannot be sunk; regs live to use).
#define ALOADV8(a0, a1) do {                                                  \
    asm volatile("global_load_dwordx4 %0, %1, off"           : "=v"(vf[0]) : "v"(a0)); \
    asm volatile("global_load_dwordx4 %0, %1, off offset:32" : "=v"(vf[1]) : "v"(a0)); \
    asm volatile("global_load_dwordx4 %0, %1, off offset:64" : "=v"(vf[2]) : "v"(a0)); \
    asm volatile("global_load_dwordx4 %0, %1, off offset:96" : "=v"(vf[3]) : "v"(a0)); \
    asm volatile("global_load_dwordx4 %0, %1, off"           : "=v"(vf[4]) : "v"(a1)); \
    asm volatile("global_load_dwordx4 %0, %1, off offset:32" : "=v"(vf[5]) : "v"(a1)); \
    asm volatile("global_load_dwordx4 %0, %1, off offset:64" : "=v"(vf[6]) : "v"(a1)); \
    asm volatile("global_load_dwordx4 %0, %1, off offset:96" : "=v"(vf[7]) : "v"(a1)); \
  } while (0)

// 16 P-values (one f32x16, already masked) -> exp -> two bf8 B-fragments.
#define PBUILD(sv, pfx, pfy) do {                                             \
    float p0_ = __builtin_amdgcn_exp2f(sv[0] - mn_);                          \
    float p1_ = __builtin_amdgcn_exp2f(sv[1] - mn_);                          \
    float p2_ = __builtin_amdgcn_exp2f(sv[2] - mn_);                          \
    float p3_ = __builtin_amdgcn_exp2f(sv[3] - mn_);                          \
    float p4_ = __builtin_amdgcn_exp2f(sv[4] - mn_);                          \
    float p5_ = __builtin_amdgcn_exp2f(sv[5] - mn_);                          \
    float p6_ = __builtin_amdgcn_exp2f(sv[6] - mn_);                          \
    float p7_ = __builtin_amdgcn_exp2f(sv[7] - mn_);                          \
    unsigned int wa0_ = cvtpk(p0_, p1_), wa1_ = cvtpk(p2_, p3_);              \
    unsigned int wb0_ = cvtpk(p4_, p5_), wb1_ = cvtpk(p6_, p7_);              \
    ls_ += ((p0_ + p1_) + (p2_ + p3_)) + ((p4_ + p5_) + (p6_ + p7_));         \
    float q0_ = __builtin_amdgcn_exp2f(sv[8] - mn_);                          \
    float q1_ = __builtin_amdgcn_exp2f(sv[9] - mn_);                          \
    float q2_ = __builtin_amdgcn_exp2f(sv[10] - mn_);                         \
    float q3_ = __builtin_amdgcn_exp2f(sv[11] - mn_);                         \
    float q4_ = __builtin_amdgcn_exp2f(sv[12] - mn_);                         \
    float q5_ = __builtin_amdgcn_exp2f(sv[13] - mn_);                         \
    float q6_ = __builtin_amdgcn_exp2f(sv[14] - mn_);                         \
    float q7_ = __builtin_amdgcn_exp2f(sv[15] - mn_);                         \
    unsigned int wc0_ = cvtpk(q0_, q1_), wc1_ = cvtpk(q2_, q3_);              \
    unsigned int wd0_ = cvtpk(q4_, q5_), wd1_ = cvtpk(q6_, q7_);              \
    ls_ += ((q0_ + q1_) + (q2_ + q3_)) + ((q4_ + q5_) + (q6_ + q7_));         \
    PSWAP(wa0_, wb0_);                                                        \
    PSWAP(wa1_, wb1_);                                                        \
    PSWAP(wc0_, wd0_);                                                        \
    PSWAP(wc1_, wd1_);                                                        \
    uint4 u0_ = {wa0_, wa1_, wb0_, wb1_};                                     \
    uint4 u1_ = {wc0_, wc1_, wd0_, wd1_};                                     \
    pfx = *reinterpret_cast<bf8*>(&u0_);                                      \
    pfy = *reinterpret_cast<bf8*>(&u1_);                                      \
  } while (0)

// One KVBLK=64 step: V issue -> wait K staged -> swizzled ds_read + QK(8) ->
// restage K(t+4) -> mask/softmax(64) -> wait V -> PV(8).
#define STEP64(t) do {                                                        \
    bf8 vf[8];                                                                \
    const uint64_t va0_ = Vb0a + (uint64_t)(t) * 128;                         \
    const uint64_t va1_ = Vb1a + (uint64_t)(t) * 128;                         \
    ALOADV8(va0_, va1_);                                                      \
    asm volatile("s_waitcnt vmcnt(8)" ::: "memory");                          \
    f32x16 s0_ = {}, s1_ = {};                                                \
    {                                                                         \
      const char* kr0_ = kbuf + ql * 128;                                     \
      const char* kr1_ = kbuf + (32 + ql) * 128;                              \
      const int x0_ = ((hi) ^ xq) << 4;                                       \
      const int x1_ = ((2 + hi) ^ xq) << 4;                                   \
      const int x2_ = ((4 + hi) ^ xq) << 4;                                   \
      const int x3_ = ((6 + hi) ^ xq) << 4;                                   \
      bf8 ka0_ = *(const bf8*)(kr0_ + x0_);                                   \
      bf8 kb0_ = *(const bf8*)(kr1_ + x0_);                                   \
      bf8 ka1_ = *(const bf8*)(kr0_ + x1_);                                   \
      bf8 kb1_ = *(const bf8*)(kr1_ + x1_);                                   \
      bf8 ka2_ = *(const bf8*)(kr0_ + x2_);                                   \
      bf8 kb2_ = *(const bf8*)(kr1_ + x2_);                                   \
      bf8 ka3_ = *(const bf8*)(kr0_ + x3_);                                   \
      bf8 kb3_ = *(const bf8*)(kr1_ + x3_);                                   \
      __builtin_amdgcn_s_setprio(1);                                          \
      s0_ = mfma32(ka0_, qf[0], s0_);  s1_ = mfma32(kb0_, qf[0], s1_);        \
      s0_ = mfma32(ka1_, qf[1], s0_);  s1_ = mfma32(kb1_, qf[1], s1_);        \
      s0_ = mfma32(ka2_, qf[2], s0_);  s1_ = mfma32(kb2_, qf[2], s1_);        \
      s0_ = mfma32(ka3_, qf[3], s0_);  s1_ = mfma32(kb3_, qf[3], s1_);        \
      __builtin_amdgcn_s_setprio(0);                                          \
    }                                                                         \
    asm volatile("s_waitcnt lgkmcnt(0)" ::: "memory");                        \
    STAGEK((t) + 4);                                                          \
    if ((t) == dt) {                                                          \
      _Pragma("unroll")                                                       \
      for (int r_ = 0; r_ < 16; ++r_) {                                       \
        int kr_ = (t) * 64 + (r_ & 3) + 8 * (r_ >> 2) + 4 * hi;               \
        s0_[r_] = (kr_ > qg) ? -1e30f : s0_[r_];                              \
        s1_[r_] = (kr_ + 32 > qg) ? -1e30f : s1_[r_];                         \
      }                                                                       \
    }                                                                         \
    float tm_ = s0_[0];                                                       \
    _Pragma("unroll")                                                         \
    for (int r_ = 1; r_ < 16; ++r_) tm_ = fmaxf(tm_, s0_[r_]);                \
    _Pragma("unroll")                                                         \
    for (int r_ = 0; r_ < 16; ++r_) tm_ = fmaxf(tm_, s1_[r_]);                \
    tm_ = fmaxf(tm_, __shfl_xor(tm_, 32));                                    \
    float mn_ = fmaxf(m, tm_);                                                \
    float al_ = __builtin_amdgcn_exp2f(m - mn_);                              \
    m = mn_;                                                                  \
    float ls_ = 0.f;                                                          \
    bf8 pfA0_, pfA1_, pfB0_, pfB1_;                                           \
    PBUILD(s0_, pfA0_, pfA1_);                                                \
    PBUILD(s1_, pfB0_, pfB1_);                                                \
    ls_ += __shfl_xor(ls_, 32);                                               \
    l = l * al_ + ls_;                                                        \
    _Pragma("unroll")                                                         \
    for (int r_ = 0; r_ < 16; ++r_) { o0[r_] *= al_; o1[r_] *= al_; }         \
    asm volatile("s_waitcnt vmcnt(8)" ::: "memory");                          \
    __builtin_amdgcn_sched_barrier(0);                                        \
    __builtin_amdgcn_s_setprio(1);                                            \
    o0 = mfma32(vf[0], pfA0_, o0);                                            \
    o0 = mfma32(vf[1], pfA1_, o0);                                            \
    o0 = mfma32(vf[2], pfB0_, o0);                                            \
    o0 = mfma32(vf[3], pfB1_, o0);                                            \
    o1 = mfma32(vf[4], pfA0_, o1);                                            \
    o1 = mfma32(vf[5], pfA1_, o1);                                            \
    o1 = mfma32(vf[6], pfB0_, o1);                                            \
    o1 = mfma32(vf[7], pfB1_, o1);                                            \
    __builtin_amdgcn_s_setprio(0);                                            \
  } while (0)

// ---- causal flash attention: paired q-tiles + split-K x4 + XCD chunking --
// KVBLK=64 (65 uniform steps per paired block). K staged to LDS (coalesced
// from per-head-contiguous Kh, XOR-swizzled); V register-direct volatile-asm
// with counted vmcnt. LDS: 4x8KB K-staging unions with the 32KB merge
// scratch (wave w's K buffer == its own sO slot; disjoint until barrier).
__global__ __launch_bounds__(256, 3) void k_attn(const unsigned short* __restrict__ Qh,
                                                 const unsigned short* __restrict__ Kh,
                                                 const unsigned short* __restrict__ Vt,
                                                 unsigned short* __restrict__ ctx) {
  const int tid = threadIdx.x;
  const int lane = tid & 63;
  const int w = tid >> 6;  // split-K wave index, 0..3
  const int ql = lane & 31, hi = lane >> 5;
  const int xq = ql & 7;

  const int L = (int)blockIdx.x;          // 0..767
  const int W = (L & 7) * 96 + (L >> 3);  // XCD-chunked work id
  const int h = W >> 6;
  const int b = W & 63;
  const size_t hd = (size_t)h * HD;

  __shared__ char smem[33792];            // [0,32K): K-staging / sO union
  char* kbuf = smem + w * 8192;           // this wave's K buffer == sO[w]
  float* sO = (float*)smem;               // [4][64][32]
  float* sM = (float*)(smem + 32768);     // [4][32]
  float* sL = (float*)(smem + 33280);     // [4][32]

  const unsigned short* Khp = Kh + (size_t)h * SEQ * 64;
  const unsigned short* Qhp = Qh + (size_t)h * SEQ * 64;
  // pre-swizzled staging source offset (shorts): lane -> row(i>>3), chunk^row
  const int kLaneOff = (lane >> 3) * 64 + ((lane & 7) ^ (lane >> 3)) * 8;
  const uint64_t Vb0base = (uint64_t)(Vt + (hd + ql) * SEQ + hi * 8);
  const uint64_t Vb1base = Vb0base + (uint64_t)32 * SEQ * 2;

  for (int ph = 0; ph < 2; ++ph) {
    const int qt = ph ? (127 - b) : b;
    const int qg = qt * 32 + ql;
    const int dt = qt >> 1;  // diagonal 64-tile
    bf8 qf[4];
    {
      const unsigned short* qp = Qhp + (size_t)qg * 64 + hi * 8;
      qf[0] = *reinterpret_cast<const bf8*>(qp);
      qf[1] = *reinterpret_cast<const bf8*>(qp + 16);
      qf[2] = *reinterpret_cast<const bf8*>(qp + 32);
      qf[3] = *reinterpret_cast<const bf8*>(qp + 48);
    }
    f32x16 o0 = {}, o1 = {};
    float m = -1e30f, l = 0.f;
    const uint64_t Vb0a = Vb0base, Vb1a = Vb1base;

    const int nt = (dt >= w) ? ((dt - w) >> 2) + 1 : 0;
    if (nt > 0) {
      STAGEK(w);
      for (int i = 0; i < nt; ++i) {
        const int t = w + 4 * i;
        STEP64(t);
      }
    }
    asm volatile("s_waitcnt vmcnt(0)" ::: "memory");  // drain over-staged K

    // ---- 4-way split-K merge via LDS ----
#pragma unroll
    for (int r = 0; r < 16; ++r) {
      int dr = (r & 3) + 8 * (r >> 2) + 4 * hi;
      sO[w * 2048 + dr * 32 + ql] = o0[r];
      sO[w * 2048 + (32 + dr) * 32 + ql] = o1[r];
    }
    if (hi == 0) { sM[w * 32 + ql] = m; sL[w * 32 + ql] = l; }
    __syncthreads();
    {
      const int q = tid & 31;
      const int dblk = tid >> 5;  // 0..7, 8 d-values each
      float m0 = sM[q], m1 = sM[32 + q], m2 = sM[64 + q], m3 = sM[96 + q];
      float mn = fmaxf(fmaxf(m0, m1), fmaxf(m2, m3));
      float a0 = __builtin_amdgcn_exp2f(m0 - mn);
      float a1 = __builtin_amdgcn_exp2f(m1 - mn);
      float a2 = __builtin_amdgcn_exp2f(m2 - mn);
      float a3 = __builtin_amdgcn_exp2f(m3 - mn);
      float inv = 1.f / (a0 * sL[q] + a1 * sL[32 + q] + a2 * sL[64 + q] + a3 * sL[96 + q]);
      a0 *= inv; a1 *= inv; a2 *= inv; a3 *= inv;
      unsigned short* cp = ctx + (size_t)(qt * 32 + q) * DM + hd + dblk * 8;
#pragma unroll
      for (int j = 0; j < 8; j += 2) {
        int d = dblk * 8 + j;
        float v0 = sO[d * 32 + q] * a0 + sO[2048 + d * 32 + q] * a1 +
                   sO[4096 + d * 32 + q] * a2 + sO[6144 + d * 32 + q] * a3;
        float v1 = sO[(d + 1) * 32 + q] * a0 + sO[2048 + (d + 1) * 32 + q] * a1 +
                   sO[4096 + (d + 1) * 32 + q] * a2 + sO[6144 + (d + 1) * 32 + q] * a3;
        *reinterpret_cast<unsigned int*>(cp + j) = cvtpk(v0, v1);
      }
    }
    __syncthreads();
  }
}

extern "C" void kernel_launch(void* const* d_in, const int* in_sizes, int n_in,
                              void* d_out, int out_size, void* d_ws, size_t ws_size,
                              hipStream_t stream) {
  const float* x  = (const float*)d_in[0];
  const float* Wq = (const float*)d_in[1];
  const float* Wk = (const float*)d_in[2];
  const float* Wv = (const float*)d_in[3];
  const float* Wo = (const float*)d_in[4];
  const float* bo = (const float*)d_in[5];

  unsigned short* xb = (unsigned short*)d_ws;
  unsigned short* wt = xb + (size_t)SEQ * DM;
  unsigned short* Qh = wt + (size_t)4 * DM * DM;
  unsigned short* Kh = Qh + (size_t)SEQ * DM;
  unsigned short* Vt = Kh + (size_t)SEQ * DM;
  unsigned short* cx = Vt + (size_t)SEQ * DM;

  const float qscale = 1.4426950408889634f / 8.0f;  // log2(e)/sqrt(HD)

  k_cvt<<<(SEQ * DM) / 1024, 256, 0, stream>>>(x, xb);
  k_tw<<<dim3(24, 24, 4), 256, 0, stream>>>(Wq, Wk, Wv, Wo, wt);
  dim3 gg(SEQ / 128, DM / 64);
  k_gemm<0><<<gg, 256, 0, stream>>>(xb, wt, Qh, nullptr, qscale);
  k_gemm<0><<<gg, 256, 0, stream>>>(xb, wt + (size_t)DM * DM, Kh, nullptr, 1.0f);
  k_gemm<1><<<gg, 256, 0, stream>>>(xb, wt + (size_t)2 * DM * DM, Vt, nullptr, 1.0f);
  k_attn<<<dim3(768), 256, 0, stream>>>(Qh, Kh, Vt, cx);
  k_gemm<2><<<gg, 256, 0, stream>>>(cx, wt + (size_t)3 * DM * DM, d_out, bo, 1.0f);
}

// Round 13
// 124.329 us; speedup vs baseline: 1.3121x; 1.0918x over previous
//
#include <hip/hip_runtime.h>
#include <stdint.h>

#define SEQ 4096
#define DM 768
#define NH 12
#define HD 64

typedef __attribute__((ext_vector_type(8))) short bf8;
typedef __attribute__((ext_vector_type(4))) float f4;
typedef __attribute__((ext_vector_type(16))) float f32x16;

static __device__ __forceinline__ f4 mfma_bf16(bf8 a, bf8 b, f4 c) {
  return __builtin_amdgcn_mfma_f32_16x16x32_bf16(a, b, c, 0, 0, 0);
}
static __device__ __forceinline__ f32x16 mfma32(bf8 a, bf8 b, f32x16 c) {
  return __builtin_amdgcn_mfma_f32_32x32x16_bf16(a, b, c, 0, 0, 0);
}

// RNE float->bf16 (bit pattern)
static __device__ __forceinline__ unsigned short f2bf(float f) {
  unsigned int u = __float_as_uint(f);
  u += 0x7FFFu + ((u >> 16) & 1u);
  return (unsigned short)(u >> 16);
}

// packed f32 pair -> bf16 pair (lo in low 16, hi in high 16)
static __device__ __forceinline__ unsigned int cvtpk(float lo, float hi) {
  unsigned int r;
  asm("v_cvt_pk_bf16_f32 %0, %1, %2" : "=v"(r) : "v"(lo), "v"(hi));
  return r;
}

static __device__ __forceinline__ void gload_lds16(const void* g, void* l) {
  __builtin_amdgcn_global_load_lds(
      (const __attribute__((address_space(1))) void*)g,
      (__attribute__((address_space(3))) void*)l, 16, 0, 0);
}

// ---- cast x (fp32) -> bf16 -----------------------------------------------
__global__ __launch_bounds__(256) void k_cvt(const float* __restrict__ x,
                                             unsigned short* __restrict__ xb) {
  int i = (blockIdx.x * 256 + threadIdx.x) * 4;
  float4 v = *reinterpret_cast<const float4*>(x + i);
  ushort4 o;
  o.x = f2bf(v.x); o.y = f2bf(v.y); o.z = f2bf(v.z); o.w = f2bf(v.w);
  *reinterpret_cast<ushort4*>(xb + i) = o;
}

// ---- transpose+cast weights: WT[z][n][k] = bf16(W[k][n]) -----------------
__global__ __launch_bounds__(256) void k_tw(const float* __restrict__ w0,
                                            const float* __restrict__ w1,
                                            const float* __restrict__ w2,
                                            const float* __restrict__ w3,
                                            unsigned short* __restrict__ wt) {
  const float* W = blockIdx.z == 0 ? w0 : blockIdx.z == 1 ? w1
                 : blockIdx.z == 2 ? w2 : w3;
  unsigned short* WT = wt + (size_t)blockIdx.z * DM * DM;
  __shared__ float t[32][33];
  int c0 = blockIdx.x * 32, r0 = blockIdx.y * 32;
  int lx = threadIdx.x & 31, ly = threadIdx.x >> 5;
#pragma unroll
  for (int rr = 0; rr < 32; rr += 8)
    t[ly + rr][lx] = W[(size_t)(r0 + ly + rr) * DM + c0 + lx];
  __syncthreads();
#pragma unroll
  for (int rr = 0; rr < 32; rr += 8)
    WT[(size_t)(c0 + ly + rr) * DM + r0 + lx] = f2bf(t[lx][ly + rr]);
}

// ---- bf16 MFMA GEMM: C[4096][768] = A[4096][768] @ Bt[768][768]^T --------
// MODE 0: store bf16 PER-HEAD [h][s][64] * scale   (Q/K; contiguous 128B rows)
// MODE 1: store bf16 V TILED [h][ktile][d][ks]     (contiguous 8KB per k-tile)
// MODE 2: store fp32 [row][768] + bias[col]
template <int MODE>
__global__ __launch_bounds__(256) void k_gemm(const unsigned short* __restrict__ A,
                                              const unsigned short* __restrict__ Bt,
                                              void* __restrict__ Cout,
                                              const float* __restrict__ bias,
                                              float scale) {
  constexpr int K = DM;
  __shared__ unsigned short sA[128 * 32];
  __shared__ unsigned short sB[64 * 32];
  const int t = threadIdx.x, lane = t & 63, w = t >> 6;
  const int wr = w >> 1, wc = w & 1;
  const int c = lane & 15, g = lane >> 4;
  const int brow = blockIdx.x * 128, bcol = blockIdx.y * 64;
  f4 acc[4][2] = {};
  for (int k0 = 0; k0 < K; k0 += 32) {
#pragma unroll
    for (int i = 0; i < 2; ++i) {
      int slot = w * 2 + i;
      int chunk = slot * 64 + lane;
      int row = chunk >> 2;
      int sl = (chunk & 3) ^ ((row >> 1) & 3);
      gload_lds16(A + (size_t)(brow + row) * K + k0 + sl * 8, &sA[slot * 512]);
    }
    {
      int chunk = w * 64 + lane;
      int row = chunk >> 2;
      int sl = (chunk & 3) ^ ((row >> 1) & 3);
      gload_lds16(Bt + (size_t)(bcol + row) * K + k0 + sl * 8, &sB[w * 512]);
    }
    __syncthreads();
    bf8 af[4], bfr[2];
#pragma unroll
    for (int m = 0; m < 4; ++m) {
      int row = wr * 64 + m * 16 + c;
      int off = row * 64 + ((g * 16) ^ (((row >> 1) & 3) << 4));
      af[m] = *reinterpret_cast<const bf8*>(reinterpret_cast<const char*>(sA) + off);
    }
#pragma unroll
    for (int n = 0; n < 2; ++n) {
      int row = wc * 32 + n * 16 + c;
      int off = row * 64 + ((g * 16) ^ (((row >> 1) & 3) << 4));
      bfr[n] = *reinterpret_cast<const bf8*>(reinterpret_cast<const char*>(sB) + off);
    }
#pragma unroll
    for (int m = 0; m < 4; ++m)
#pragma unroll
      for (int n = 0; n < 2; ++n)
        acc[m][n] = mfma_bf16(af[m], bfr[n], acc[m][n]);
    __syncthreads();
  }
#pragma unroll
  for (int m = 0; m < 4; ++m) {
#pragma unroll
    for (int n = 0; n < 2; ++n) {
      int col = bcol + wc * 32 + n * 16 + c;
      int row0 = brow + wr * 64 + m * 16 + g * 4;
      if (MODE == 0) {
        unsigned short* C = (unsigned short*)Cout;
        int h = col >> 6, d = col & 63;
#pragma unroll
        for (int r = 0; r < 4; ++r)
          C[((size_t)h * SEQ + row0 + r) * 64 + d] = f2bf(acc[m][n][r] * scale);
      } else if (MODE == 1) {
        unsigned short* C = (unsigned short*)Cout;
        int h = col >> 6, d = col & 63;
        ushort4 p;
        p.x = f2bf(acc[m][n][0]); p.y = f2bf(acc[m][n][1]);
        p.z = f2bf(acc[m][n][2]); p.w = f2bf(acc[m][n][3]);
        // row0 = k index; tile = row0>>6, ks = row0&63 (row0%4==0 -> in-tile)
        *reinterpret_cast<ushort4*>(
            C + ((((size_t)h * 64 + (row0 >> 6)) * 64 + d) * 64 + (row0 & 63))) = p;
      } else {
        float* C = (float*)Cout;
#pragma unroll
        for (int r = 0; r < 4; ++r)
          C[(size_t)(row0 + r) * DM + col] = acc[m][n][r] + bias[col];
      }
    }
  }
}

// ---- attention helpers ----------------------------------------------------
#define PSWAP(a, b) asm volatile("v_permlane32_swap_b32 %0, %1" : "+v"(a), "+v"(b))
#define SGB() __builtin_amdgcn_sched_barrier(0)

// Stage a 64x64 bf16 tile (contiguous 8KB) into LDS, pre-swizzled source
// (chunk ^= row&7) so linear LDS dest + swizzled ds_read match (rule #21).
#define STAGE8K(srcbase, tile, dst) do {                                      \
    const unsigned short* s_ = (srcbase) + (size_t)(tile) * 4096 + kLaneOff;  \
    _Pragma("unroll")                                                         \
    for (int j_ = 0; j_ < 8; ++j_)                                            \
      gload_lds16(s_ + j_ * 512, (dst) + j_ * 1024);                          \
  } while (0)

// 16 P-values (one f32x16, already masked) -> exp -> two bf8 B-fragments.
#define PBUILD(sv, pfx, pfy) do {                                             \
    float p0_ = __builtin_amdgcn_exp2f(sv[0] - mn_);                          \
    float p1_ = __builtin_amdgcn_exp2f(sv[1] - mn_);                          \
    float p2_ = __builtin_amdgcn_exp2f(sv[2] - mn_);                          \
    float p3_ = __builtin_amdgcn_exp2f(sv[3] - mn_);                          \
    float p4_ = __builtin_amdgcn_exp2f(sv[4] - mn_);                          \
    float p5_ = __builtin_amdgcn_exp2f(sv[5] - mn_);                          \
    float p6_ = __builtin_amdgcn_exp2f(sv[6] - mn_);                          \
    float p7_ = __builtin_amdgcn_exp2f(sv[7] - mn_);                          \
    unsigned int wa0_ = cvtpk(p0_, p1_), wa1_ = cvtpk(p2_, p3_);              \
    unsigned int wb0_ = cvtpk(p4_, p5_), wb1_ = cvtpk(p6_, p7_);              \
    ls_ += ((p0_ + p1_) + (p2_ + p3_)) + ((p4_ + p5_) + (p6_ + p7_));         \
    float q0_ = __builtin_amdgcn_exp2f(sv[8] - mn_);                          \
    float q1_ = __builtin_amdgcn_exp2f(sv[9] - mn_);                          \
    float q2_ = __builtin_amdgcn_exp2f(sv[10] - mn_);                         \
    float q3_ = __builtin_amdgcn_exp2f(sv[11] - mn_);                         \
    float q4_ = __builtin_amdgcn_exp2f(sv[12] - mn_);                         \
    float q5_ = __builtin_amdgcn_exp2f(sv[13] - mn_);                         \
    float q6_ = __builtin_amdgcn_exp2f(sv[14] - mn_);                         \
    float q7_ = __builtin_amdgcn_exp2f(sv[15] - mn_);                         \
    unsigned int wc0_ = cvtpk(q0_, q1_), wc1_ = cvtpk(q2_, q3_);              \
    unsigned int wd0_ = cvtpk(q4_, q5_), wd1_ = cvtpk(q6_, q7_);              \
    ls_ += ((q0_ + q1_) + (q2_ + q3_)) + ((q4_ + q5_) + (q6_ + q7_));         \
    PSWAP(wa0_, wb0_);                                                        \
    PSWAP(wa1_, wb1_);                                                        \
    PSWAP(wc0_, wd0_);                                                        \
    PSWAP(wc1_, wd1_);                                                        \
    uint4 u0_ = {wa0_, wa1_, wb0_, wb1_};                                     \
    uint4 u1_ = {wc0_, wc1_, wd0_, wd1_};                                     \
    pfx = *reinterpret_cast<bf8*>(&u0_);                                      \
    pfy = *reinterpret_cast<bf8*>(&u1_);                                      \
  } while (0)

#define FMAX8(v, i0) fmaxf(fmaxf(fmaxf(v[i0], v[i0+1]), fmaxf(v[i0+2], v[i0+3])), \
                           fmaxf(fmaxf(v[i0+4], v[i0+5]), fmaxf(v[i0+6], v[i0+7])))

// One KVBLK=64 step. Each buffer's ds_reads are fenced (SGB/lgkmcnt(0)/SGB)
// BEFORE its restage overwrites it, and before the MFMAs that consume them
// (rule #18: pin reads above, MFMAs below the wait). K and V fragment sets
// are never simultaneously live.
#define STEP64(t, stage_) do {                                                \
    asm volatile("s_waitcnt vmcnt(0)" ::: "memory");                          \
    SGB();                                                                    \
    const int x0_ = ((hi) ^ xq) << 4;                                         \
    const int x1_ = ((2 + hi) ^ xq) << 4;                                     \
    const int x2_ = ((4 + hi) ^ xq) << 4;                                     \
    const int x3_ = ((6 + hi) ^ xq) << 4;                                     \
    const char* kr0_ = kbuf + ql * 128;                                       \
    const char* kr1_ = kbuf + (32 + ql) * 128;                                \
    bf8 ka0_ = *(const bf8*)(kr0_ + x0_);                                     \
    bf8 kb0_ = *(const bf8*)(kr1_ + x0_);                                     \
    bf8 ka1_ = *(const bf8*)(kr0_ + x1_);                                     \
    bf8 kb1_ = *(const bf8*)(kr1_ + x1_);                                     \
    bf8 ka2_ = *(const bf8*)(kr0_ + x2_);                                     \
    bf8 kb2_ = *(const bf8*)(kr1_ + x2_);                                     \
    bf8 ka3_ = *(const bf8*)(kr0_ + x3_);                                     \
    bf8 kb3_ = *(const bf8*)(kr1_ + x3_);                                     \
    SGB();                                                                    \
    asm volatile("s_waitcnt lgkmcnt(0)" ::: "memory");                        \
    SGB();                                                                    \
    if (stage_) STAGE8K(Khp, (t) + 4, kbuf);                                  \
    f32x16 s0_ = {}, s1_ = {};                                                \
    __builtin_amdgcn_s_setprio(1);                                            \
    s0_ = mfma32(ka0_, qf[0], s0_);  s1_ = mfma32(kb0_, qf[0], s1_);          \
    s0_ = mfma32(ka1_, qf[1], s0_);  s1_ = mfma32(kb1_, qf[1], s1_);          \
    s0_ = mfma32(ka2_, qf[2], s0_);  s1_ = mfma32(kb2_, qf[2], s1_);          \
    s0_ = mfma32(ka3_, qf[3], s0_);  s1_ = mfma32(kb3_, qf[3], s1_);          \
    __builtin_amdgcn_s_setprio(0);                                            \
    if ((t) == dt) {                                                          \
      _Pragma("unroll")                                                       \
      for (int r_ = 0; r_ < 16; ++r_) {                                       \
        int kr_ = (t) * 64 + (r_ & 3) + 8 * (r_ >> 2) + 4 * hi;               \
        s0_[r_] = (kr_ > qg) ? -1e30f : s0_[r_];                              \
        s1_[r_] = (kr_ + 32 > qg) ? -1e30f : s1_[r_];                         \
      }                                                                       \
    }                                                                         \
    float tm_ = fmaxf(fmaxf(FMAX8(s0_, 0), FMAX8(s0_, 8)),                    \
                      fmaxf(FMAX8(s1_, 0), FMAX8(s1_, 8)));                   \
    tm_ = fmaxf(tm_, __shfl_xor(tm_, 32));                                    \
    float mn_ = fmaxf(m, tm_);                                                \
    float al_ = __builtin_amdgcn_exp2f(m - mn_);                              \
    m = mn_;                                                                  \
    float ls_ = 0.f;                                                          \
    bf8 pfA0_, pfA1_, pfB0_, pfB1_;                                           \
    PBUILD(s0_, pfA0_, pfA1_);                                                \
    PBUILD(s1_, pfB0_, pfB1_);                                                \
    ls_ += __shfl_xor(ls_, 32);                                               \
    l = l * al_ + ls_;                                                        \
    const char* vr0_ = vbuf + ql * 128;                                       \
    const char* vr1_ = vbuf + (32 + ql) * 128;                                \
    bf8 va0_ = *(const bf8*)(vr0_ + x0_);                                     \
    bf8 va1_ = *(const bf8*)(vr0_ + x1_);                                     \
    bf8 va2_ = *(const bf8*)(vr0_ + x2_);                                     \
    bf8 va3_ = *(const bf8*)(vr0_ + x3_);                                     \
    bf8 vb0_ = *(const bf8*)(vr1_ + x0_);                                     \
    bf8 vb1_ = *(const bf8*)(vr1_ + x1_);                                     \
    bf8 vb2_ = *(const bf8*)(vr1_ + x2_);                                     \
    bf8 vb3_ = *(const bf8*)(vr1_ + x3_);                                     \
    SGB();                                                                    \
    asm volatile("s_waitcnt lgkmcnt(0)" ::: "memory");                        \
    SGB();                                                                    \
    if (stage_) STAGE8K(Vtp, (t) + 4, vbuf);                                  \
    _Pragma("unroll")                                                         \
    for (int r_ = 0; r_ < 16; ++r_) { o0[r_] *= al_; o1[r_] *= al_; }         \
    __builtin_amdgcn_s_setprio(1);                                            \
    o0 = mfma32(va0_, pfA0_, o0);                                             \
    o0 = mfma32(va1_, pfA1_, o0);                                             \
    o0 = mfma32(va2_, pfB0_, o0);                                             \
    o0 = mfma32(va3_, pfB1_, o0);                                             \
    o1 = mfma32(vb0_, pfA0_, o1);                                             \
    o1 = mfma32(vb1_, pfA1_, o1);                                             \
    o1 = mfma32(vb2_, pfB0_, o1);                                             \
    o1 = mfma32(vb3_, pfB1_, o1);                                             \
    __builtin_amdgcn_s_setprio(0);                                            \
  } while (0)

// ---- causal flash attention: paired q-tiles + split-K x4 + XCD chunking --
// KVBLK=64. K and V LDS-staged from contiguous 8KB tiles (coalesced
// gload_lds, XOR-swizzled both sides), one step ahead, no over-staging.
// Every LDS-read block is SGB/lgkmcnt(0)/SGB-fenced before its buffer is
// restaged and before its consuming MFMAs. LDS map: kbufs [0,32K) (wave
// w's kbuf == its OWN sO slot), vbufs [32K,64K), sM/sL at 64K.
__global__ __launch_bounds__(256, 2) void k_attn(const unsigned short* __restrict__ Qh,
                                                 const unsigned short* __restrict__ Kh,
                                                 const unsigned short* __restrict__ Vt,
                                                 unsigned short* __restrict__ ctx) {
  const int tid = threadIdx.x;
  const int lane = tid & 63;
  const int w = tid >> 6;  // split-K wave index, 0..3
  const int ql = lane & 31, hi = lane >> 5;
  const int xq = ql & 7;

  const int L = (int)blockIdx.x;          // 0..767
  const int W = (L & 7) * 96 + (L >> 3);  // XCD-chunked work id
  const int h = W >> 6;
  const int b = W & 63;

  __shared__ __align__(16) char smem[66560];
  char* kbuf = smem + w * 8192;           // own sO slot union
  char* vbuf = smem + 32768 + w * 8192;
  float* sO = (float*)smem;               // [4][64][32]
  float* sM = (float*)(smem + 65536);     // [4][32]
  float* sL = (float*)(smem + 66048);     // [4][32]

  const unsigned short* Khp = Kh + (size_t)h * SEQ * 64;
  const unsigned short* Qhp = Qh + (size_t)h * SEQ * 64;
  const unsigned short* Vtp = Vt + (size_t)h * SEQ * 64;  // tiled [64][64][64]
  // pre-swizzled staging source offset (shorts): row = lane>>3, chunk^row
  const int kLaneOff = (lane >> 3) * 64 + ((lane & 7) ^ (lane >> 3)) * 8;

  for (int ph = 0; ph < 2; ++ph) {
    const int qt = ph ? (127 - b) : b;
    const int qg = qt * 32 + ql;
    const int dt = qt >> 1;  // diagonal 64-tile
    bf8 qf[4];
    {
      const unsigned short* qp = Qhp + (size_t)qg * 64 + hi * 8;
      qf[0] = *reinterpret_cast<const bf8*>(qp);
      qf[1] = *reinterpret_cast<const bf8*>(qp + 16);
      qf[2] = *reinterpret_cast<const bf8*>(qp + 32);
      qf[3] = *reinterpret_cast<const bf8*>(qp + 48);
    }
    f32x16 o0 = {}, o1 = {};
    float m = -1e30f, l = 0.f;

    const int nt = (dt >= w) ? ((dt - w) >> 2) + 1 : 0;
    if (nt > 0) {
      STAGE8K(Khp, w, kbuf);
      STAGE8K(Vtp, w, vbuf);
      for (int i = 0; i < nt; ++i) {
        const int t = w + 4 * i;
        STEP64(t, (i + 1 < nt));
      }
    }
    __syncthreads();  // all staging consumed; buffers reusable as sO

    // ---- 4-way split-K merge via LDS (sO[w] == wave w's own kbuf) ----
#pragma unroll
    for (int r = 0; r < 16; ++r) {
      int dr = (r & 3) + 8 * (r >> 2) + 4 * hi;
      sO[w * 2048 + dr * 32 + ql] = o0[r];
      sO[w * 2048 + (32 + dr) * 32 + ql] = o1[r];
    }
    if (hi == 0) { sM[w * 32 + ql] = m; sL[w * 32 + ql] = l; }
    __syncthreads();
    {
      const int q = tid & 31;
      const int dblk = tid >> 5;  // 0..7, 8 d-values each
      float m0 = sM[q], m1 = sM[32 + q], m2 = sM[64 + q], m3 = sM[96 + q];
      float mn = fmaxf(fmaxf(m0, m1), fmaxf(m2, m3));
      float a0 = __builtin_amdgcn_exp2f(m0 - mn);
      float a1 = __builtin_amdgcn_exp2f(m1 - mn);
      float a2 = __builtin_amdgcn_exp2f(m2 - mn);
      float a3 = __builtin_amdgcn_exp2f(m3 - mn);
      float inv = 1.f / (a0 * sL[q] + a1 * sL[32 + q] + a2 * sL[64 + q] + a3 * sL[96 + q]);
      a0 *= inv; a1 *= inv; a2 *= inv; a3 *= inv;
      unsigned short* cp = ctx + (size_t)(qt * 32 + q) * DM + h * HD + dblk * 8;
#pragma unroll
      for (int j = 0; j < 8; j += 2) {
        int d = dblk * 8 + j;
        float v0 = sO[d * 32 + q] * a0 + sO[2048 + d * 32 + q] * a1 +
                   sO[4096 + d * 32 + q] * a2 + sO[6144 + d * 32 + q] * a3;
        float v1 = sO[(d + 1) * 32 + q] * a0 + sO[2048 + (d + 1) * 32 + q] * a1 +
                   sO[4096 + (d + 1) * 32 + q] * a2 + sO[6144 + (d + 1) * 32 + q] * a3;
        *reinterpret_cast<unsigned int*>(cp + j) = cvtpk(v0, v1);
      }
    }
    __syncthreads();  // merge reads done before phase-2 restage
  }
}

extern "C" void kernel_launch(void* const* d_in, const int* in_sizes, int n_in,
                              void* d_out, int out_size, void* d_ws, size_t ws_size,
                              hipStream_t stream) {
  const float* x  = (const float*)d_in[0];
  const float* Wq = (const float*)d_in[1];
  const float* Wk = (const float*)d_in[2];
  const float* Wv = (const float*)d_in[3];
  const float* Wo = (const float*)d_in[4];
  const float* bo = (const float*)d_in[5];

  unsigned short* xb = (unsigned short*)d_ws;
  unsigned short* wt = xb + (size_t)SEQ * DM;
  unsigned short* Qh = wt + (size_t)4 * DM * DM;
  unsigned short* Kh = Qh + (size_t)SEQ * DM;
  unsigned short* Vt = Kh + (size_t)SEQ * DM;
  unsigned short* cx = Vt + (size_t)SEQ * DM;

  const float qscale = 1.4426950408889634f / 8.0f;  // log2(e)/sqrt(HD)

  k_cvt<<<(SEQ * DM) / 1024, 256, 0, stream>>>(x, xb);
  k_tw<<<dim3(24, 24, 4), 256, 0, stream>>>(Wq, Wk, Wv, Wo, wt);
  dim3 gg(SEQ / 128, DM / 64);
  k_gemm<0><<<gg, 256, 0, stream>>>(xb, wt, Qh, nullptr, qscale);
  k_gemm<0><<<gg, 256, 0, stream>>>(xb, wt + (size_t)DM * DM, Kh, nullptr, 1.0f);
  k_gemm<1><<<gg, 256, 0, stream>>>(xb, wt + (size_t)2 * DM * DM, Vt, nullptr, 1.0f);
  k_attn<<<dim3(768), 256, 0, stream>>>(Qh, Kh, Vt, cx);
  k_gemm<2><<<gg, 256, 0, stream>>>(cx, wt + (size_t)3 * DM * DM, d_out, bo, 1.0f);
}

// Round 14
// 122.665 us; speedup vs baseline: 1.3299x; 1.0136x over previous
//
#include <hip/hip_runtime.h>
#include <stdint.h>

#define SEQ 4096
#define DM 768
#define NH 12
#define HD 64

typedef __attribute__((ext_vector_type(8))) short bf8;
typedef __attribute__((ext_vector_type(4))) float f4;
typedef __attribute__((ext_vector_type(16))) float f32x16;

static __device__ __forceinline__ f4 mfma_bf16(bf8 a, bf8 b, f4 c) {
  return __builtin_amdgcn_mfma_f32_16x16x32_bf16(a, b, c, 0, 0, 0);
}
static __device__ __forceinline__ f32x16 mfma32(bf8 a, bf8 b, f32x16 c) {
  return __builtin_amdgcn_mfma_f32_32x32x16_bf16(a, b, c, 0, 0, 0);
}

// RNE float->bf16 (bit pattern)
static __device__ __forceinline__ unsigned short f2bf(float f) {
  unsigned int u = __float_as_uint(f);
  u += 0x7FFFu + ((u >> 16) & 1u);
  return (unsigned short)(u >> 16);
}

// packed f32 pair -> bf16 pair (lo in low 16, hi in high 16)
static __device__ __forceinline__ unsigned int cvtpk(float lo, float hi) {
  unsigned int r;
  asm("v_cvt_pk_bf16_f32 %0, %1, %2" : "=v"(r) : "v"(lo), "v"(hi));
  return r;
}

static __device__ __forceinline__ void gload_lds16(const void* g, void* l) {
  __builtin_amdgcn_global_load_lds(
      (const __attribute__((address_space(1))) void*)g,
      (__attribute__((address_space(3))) void*)l, 16, 0, 0);
}

// ---- cast x (fp32) -> bf16 -----------------------------------------------
__global__ __launch_bounds__(256) void k_cvt(const float* __restrict__ x,
                                             unsigned short* __restrict__ xb) {
  int i = (blockIdx.x * 256 + threadIdx.x) * 4;
  float4 v = *reinterpret_cast<const float4*>(x + i);
  ushort4 o;
  o.x = f2bf(v.x); o.y = f2bf(v.y); o.z = f2bf(v.z); o.w = f2bf(v.w);
  *reinterpret_cast<ushort4*>(xb + i) = o;
}

// ---- transpose+cast weights: WT[z][n][k] = bf16(W[k][n]) -----------------
__global__ __launch_bounds__(256) void k_tw(const float* __restrict__ w0,
                                            const float* __restrict__ w1,
                                            const float* __restrict__ w2,
                                            const float* __restrict__ w3,
                                            unsigned short* __restrict__ wt) {
  const float* W = blockIdx.z == 0 ? w0 : blockIdx.z == 1 ? w1
                 : blockIdx.z == 2 ? w2 : w3;
  unsigned short* WT = wt + (size_t)blockIdx.z * DM * DM;
  __shared__ float t[32][33];
  int c0 = blockIdx.x * 32, r0 = blockIdx.y * 32;
  int lx = threadIdx.x & 31, ly = threadIdx.x >> 5;
#pragma unroll
  for (int rr = 0; rr < 32; rr += 8)
    t[ly + rr][lx] = W[(size_t)(r0 + ly + rr) * DM + c0 + lx];
  __syncthreads();
#pragma unroll
  for (int rr = 0; rr < 32; rr += 8)
    WT[(size_t)(c0 + ly + rr) * DM + r0 + lx] = f2bf(t[lx][ly + rr]);
}

// ---- bf16 MFMA GEMM: C[4096][768] = A[4096][768] @ Bt[768][768]^T --------
// MODE 0: store bf16 PER-HEAD [h][s][64] * scale   (Q/K; contiguous 128B rows)
// MODE 1: store bf16 V TILED [h][ktile][d][ks]     (contiguous 8KB per k-tile)
// MODE 2: store fp32 [row][768] + bias[col]
template <int MODE>
__global__ __launch_bounds__(256) void k_gemm(const unsigned short* __restrict__ A,
                                              const unsigned short* __restrict__ Bt,
                                              void* __restrict__ Cout,
                                              const float* __restrict__ bias,
                                              float scale) {
  constexpr int K = DM;
  __shared__ unsigned short sA[128 * 32];
  __shared__ unsigned short sB[64 * 32];
  const int t = threadIdx.x, lane = t & 63, w = t >> 6;
  const int wr = w >> 1, wc = w & 1;
  const int c = lane & 15, g = lane >> 4;
  const int brow = blockIdx.x * 128, bcol = blockIdx.y * 64;
  f4 acc[4][2] = {};
  for (int k0 = 0; k0 < K; k0 += 32) {
#pragma unroll
    for (int i = 0; i < 2; ++i) {
      int slot = w * 2 + i;
      int chunk = slot * 64 + lane;
      int row = chunk >> 2;
      int sl = (chunk & 3) ^ ((row >> 1) & 3);
      gload_lds16(A + (size_t)(brow + row) * K + k0 + sl * 8, &sA[slot * 512]);
    }
    {
      int chunk = w * 64 + lane;
      int row = chunk >> 2;
      int sl = (chunk & 3) ^ ((row >> 1) & 3);
      gload_lds16(Bt + (size_t)(bcol + row) * K + k0 + sl * 8, &sB[w * 512]);
    }
    __syncthreads();
    bf8 af[4], bfr[2];
#pragma unroll
    for (int m = 0; m < 4; ++m) {
      int row = wr * 64 + m * 16 + c;
      int off = row * 64 + ((g * 16) ^ (((row >> 1) & 3) << 4));
      af[m] = *reinterpret_cast<const bf8*>(reinterpret_cast<const char*>(sA) + off);
    }
#pragma unroll
    for (int n = 0; n < 2; ++n) {
      int row = wc * 32 + n * 16 + c;
      int off = row * 64 + ((g * 16) ^ (((row >> 1) & 3) << 4));
      bfr[n] = *reinterpret_cast<const bf8*>(reinterpret_cast<const char*>(sB) + off);
    }
#pragma unroll
    for (int m = 0; m < 4; ++m)
#pragma unroll
      for (int n = 0; n < 2; ++n)
        acc[m][n] = mfma_bf16(af[m], bfr[n], acc[m][n]);
    __syncthreads();
  }
#pragma unroll
  for (int m = 0; m < 4; ++m) {
#pragma unroll
    for (int n = 0; n < 2; ++n) {
      int col = bcol + wc * 32 + n * 16 + c;
      int row0 = brow + wr * 64 + m * 16 + g * 4;
      if (MODE == 0) {
        unsigned short* C = (unsigned short*)Cout;
        int h = col >> 6, d = col & 63;
#pragma unroll
        for (int r = 0; r < 4; ++r)
          C[((size_t)h * SEQ + row0 + r) * 64 + d] = f2bf(acc[m][n][r] * scale);
      } else if (MODE == 1) {
        unsigned short* C = (unsigned short*)Cout;
        int h = col >> 6, d = col & 63;
        ushort4 p;
        p.x = f2bf(acc[m][n][0]); p.y = f2bf(acc[m][n][1]);
        p.z = f2bf(acc[m][n][2]); p.w = f2bf(acc[m][n][3]);
        // row0 = k index; tile = row0>>6, ks = row0&63 (row0%4==0 -> in-tile)
        *reinterpret_cast<ushort4*>(
            C + ((((size_t)h * 64 + (row0 >> 6)) * 64 + d) * 64 + (row0 & 63))) = p;
      } else {
        float* C = (float*)Cout;
#pragma unroll
        for (int r = 0; r < 4; ++r)
          C[(size_t)(row0 + r) * DM + col] = acc[m][n][r] + bias[col];
      }
    }
  }
}

// ---- attention helpers ----------------------------------------------------
#define PSWAP(a, b) asm volatile("v_permlane32_swap_b32 %0, %1" : "+v"(a), "+v"(b))
#define SGB() __builtin_amdgcn_sched_barrier(0)

// Stage a 64x64 bf16 tile (contiguous 8KB) into LDS, pre-swizzled source
// (chunk ^= row&7) so linear LDS dest + swizzled ds_read match (rule #21).
#define STAGE8K(srcbase, tile, dst) do {                                      \
    const unsigned short* s_ = (srcbase) + (size_t)(tile) * 4096 + kLaneOff;  \
    _Pragma("unroll")                                                         \
    for (int j_ = 0; j_ < 8; ++j_)                                            \
      gload_lds16(s_ + j_ * 512, (dst) + j_ * 1024);                          \
  } while (0)

// 16 P-values (one f32x16, already masked) -> exp -> two bf8 B-fragments.
#define PBUILD(sv, pfx, pfy) do {                                             \
    float p0_ = __builtin_amdgcn_exp2f(sv[0] - mn_);                          \
    float p1_ = __builtin_amdgcn_exp2f(sv[1] - mn_);                          \
    float p2_ = __builtin_amdgcn_exp2f(sv[2] - mn_);                          \
    float p3_ = __builtin_amdgcn_exp2f(sv[3] - mn_);                          \
    float p4_ = __builtin_amdgcn_exp2f(sv[4] - mn_);                          \
    float p5_ = __builtin_amdgcn_exp2f(sv[5] - mn_);                          \
    float p6_ = __builtin_amdgcn_exp2f(sv[6] - mn_);                          \
    float p7_ = __builtin_amdgcn_exp2f(sv[7] - mn_);                          \
    unsigned int wa0_ = cvtpk(p0_, p1_), wa1_ = cvtpk(p2_, p3_);              \
    unsigned int wb0_ = cvtpk(p4_, p5_), wb1_ = cvtpk(p6_, p7_);              \
    ls_ += ((p0_ + p1_) + (p2_ + p3_)) + ((p4_ + p5_) + (p6_ + p7_));         \
    float q0_ = __builtin_amdgcn_exp2f(sv[8] - mn_);                          \
    float q1_ = __builtin_amdgcn_exp2f(sv[9] - mn_);                          \
    float q2_ = __builtin_amdgcn_exp2f(sv[10] - mn_);                         \
    float q3_ = __builtin_amdgcn_exp2f(sv[11] - mn_);                         \
    float q4_ = __builtin_amdgcn_exp2f(sv[12] - mn_);                         \
    float q5_ = __builtin_amdgcn_exp2f(sv[13] - mn_);                         \
    float q6_ = __builtin_amdgcn_exp2f(sv[14] - mn_);                         \
    float q7_ = __builtin_amdgcn_exp2f(sv[15] - mn_);                         \
    unsigned int wc0_ = cvtpk(q0_, q1_), wc1_ = cvtpk(q2_, q3_);              \
    unsigned int wd0_ = cvtpk(q4_, q5_), wd1_ = cvtpk(q6_, q7_);              \
    ls_ += ((q0_ + q1_) + (q2_ + q3_)) + ((q4_ + q5_) + (q6_ + q7_));         \
    PSWAP(wa0_, wb0_);                                                        \
    PSWAP(wa1_, wb1_);                                                        \
    PSWAP(wc0_, wd0_);                                                        \
    PSWAP(wc1_, wd1_);                                                        \
    uint4 u0_ = {wa0_, wa1_, wb0_, wb1_};                                     \
    uint4 u1_ = {wc0_, wc1_, wd0_, wd1_};                                     \
    pfx = *reinterpret_cast<bf8*>(&u0_);                                      \
    pfy = *reinterpret_cast<bf8*>(&u1_);                                      \
  } while (0)

#define FMAX8(v, i0) fmaxf(fmaxf(fmaxf(v[i0], v[i0+1]), fmaxf(v[i0+2], v[i0+3])), \
                           fmaxf(fmaxf(v[i0+4], v[i0+5]), fmaxf(v[i0+6], v[i0+7])))

// Cross-half (lane i <-> i+32) reduce via permlane32_swap. The opaque asm
// copy forces 'cp' into a register DISTINCT from 'x' (R7 lesson: without
// it the compiler coalesces the two operands and the swap self-cancels).
#define XHALF_MAX(x) do {                                                     \
    float cp_ = (x);                                                          \
    asm volatile("" : "+v"(cp_));                                             \
    PSWAP((x), cp_);                                                          \
    (x) = fmaxf((x), cp_);                                                    \
  } while (0)
#define XHALF_ADD(x) do {                                                     \
    float cp_ = (x);                                                          \
    asm volatile("" : "+v"(cp_));                                             \
    PSWAP((x), cp_);                                                          \
    (x) = (x) + cp_;                                                          \
  } while (0)

// One KVBLK=64 step. Each buffer's ds_reads are fenced (SGB/lgkmcnt(0)/SGB)
// BEFORE its restage overwrites it, and before the MFMAs that consume them
// (rule #18). Defer-max (T13, THR=8 in log2 domain): skip m-update and
// O-rescale while the tile max stays within 8 of the running max.
#define STEP64(t, stage_) do {                                                \
    asm volatile("s_waitcnt vmcnt(0)" ::: "memory");                          \
    SGB();                                                                    \
    const int x0_ = ((hi) ^ xq) << 4;                                         \
    const int x1_ = ((2 + hi) ^ xq) << 4;                                     \
    const int x2_ = ((4 + hi) ^ xq) << 4;                                     \
    const int x3_ = ((6 + hi) ^ xq) << 4;                                     \
    const char* kr0_ = kbuf + ql * 128;                                       \
    const char* kr1_ = kbuf + (32 + ql) * 128;                                \
    bf8 ka0_ = *(const bf8*)(kr0_ + x0_);                                     \
    bf8 kb0_ = *(const bf8*)(kr1_ + x0_);                                     \
    bf8 ka1_ = *(const bf8*)(kr0_ + x1_);                                     \
    bf8 kb1_ = *(const bf8*)(kr1_ + x1_);                                     \
    bf8 ka2_ = *(const bf8*)(kr0_ + x2_);                                     \
    bf8 kb2_ = *(const bf8*)(kr1_ + x2_);                                     \
    bf8 ka3_ = *(const bf8*)(kr0_ + x3_);                                     \
    bf8 kb3_ = *(const bf8*)(kr1_ + x3_);                                     \
    SGB();                                                                    \
    asm volatile("s_waitcnt lgkmcnt(0)" ::: "memory");                        \
    SGB();                                                                    \
    if (stage_) STAGE8K(Khp, (t) + 4, kbuf);                                  \
    f32x16 s0_ = {}, s1_ = {};                                                \
    __builtin_amdgcn_s_setprio(1);                                            \
    s0_ = mfma32(ka0_, qf[0], s0_);  s1_ = mfma32(kb0_, qf[0], s1_);          \
    s0_ = mfma32(ka1_, qf[1], s0_);  s1_ = mfma32(kb1_, qf[1], s1_);          \
    s0_ = mfma32(ka2_, qf[2], s0_);  s1_ = mfma32(kb2_, qf[2], s1_);          \
    s0_ = mfma32(ka3_, qf[3], s0_);  s1_ = mfma32(kb3_, qf[3], s1_);          \
    __builtin_amdgcn_s_setprio(0);                                            \
    if ((t) == dt) {                                                          \
      _Pragma("unroll")                                                       \
      for (int r_ = 0; r_ < 16; ++r_) {                                       \
        int kr_ = (t) * 64 + (r_ & 3) + 8 * (r_ >> 2) + 4 * hi;               \
        s0_[r_] = (kr_ > qg) ? -1e30f : s0_[r_];                              \
        s1_[r_] = (kr_ + 32 > qg) ? -1e30f : s1_[r_];                         \
      }                                                                       \
    }                                                                         \
    float tm_ = fmaxf(fmaxf(FMAX8(s0_, 0), FMAX8(s0_, 8)),                    \
                      fmaxf(FMAX8(s1_, 0), FMAX8(s1_, 8)));                   \
    XHALF_MAX(tm_);                                                           \
    float mn_, al_;                                                           \
    if (__all(tm_ <= m + 8.f)) {                                              \
      mn_ = m;                                                                \
      al_ = 1.0f;                                                             \
    } else {                                                                  \
      mn_ = fmaxf(m, tm_);                                                    \
      al_ = __builtin_amdgcn_exp2f(m - mn_);                                  \
      m = mn_;                                                                \
      _Pragma("unroll")                                                       \
      for (int r_ = 0; r_ < 16; ++r_) { o0[r_] *= al_; o1[r_] *= al_; }       \
    }                                                                         \
    float ls_ = 0.f;                                                          \
    bf8 pfA0_, pfA1_, pfB0_, pfB1_;                                           \
    PBUILD(s0_, pfA0_, pfA1_);                                                \
    PBUILD(s1_, pfB0_, pfB1_);                                                \
    XHALF_ADD(ls_);                                                           \
    l = l * al_ + ls_;                                                        \
    const char* vr0_ = vbuf + ql * 128;                                       \
    const char* vr1_ = vbuf + (32 + ql) * 128;                                \
    bf8 va0_ = *(const bf8*)(vr0_ + x0_);                                     \
    bf8 va1_ = *(const bf8*)(vr0_ + x1_);                                     \
    bf8 va2_ = *(const bf8*)(vr0_ + x2_);                                     \
    bf8 va3_ = *(const bf8*)(vr0_ + x3_);                                     \
    bf8 vb0_ = *(const bf8*)(vr1_ + x0_);                                     \
    bf8 vb1_ = *(const bf8*)(vr1_ + x1_);                                     \
    bf8 vb2_ = *(const bf8*)(vr1_ + x2_);                                     \
    bf8 vb3_ = *(const bf8*)(vr1_ + x3_);                                     \
    SGB();                                                                    \
    asm volatile("s_waitcnt lgkmcnt(0)" ::: "memory");                        \
    SGB();                                                                    \
    if (stage_) STAGE8K(Vtp, (t) + 4, vbuf);                                  \
    __builtin_amdgcn_s_setprio(1);                                            \
    o0 = mfma32(va0_, pfA0_, o0);                                             \
    o0 = mfma32(va1_, pfA1_, o0);                                             \
    o0 = mfma32(va2_, pfB0_, o0);                                             \
    o0 = mfma32(va3_, pfB1_, o0);                                             \
    o1 = mfma32(vb0_, pfA0_, o1);                                             \
    o1 = mfma32(vb1_, pfA1_, o1);                                             \
    o1 = mfma32(vb2_, pfB0_, o1);                                             \
    o1 = mfma32(vb3_, pfB1_, o1);                                             \
    __builtin_amdgcn_s_setprio(0);                                            \
  } while (0)

// ---- causal flash attention: paired q-tiles + split-K x4 + XCD chunking --
// KVBLK=64. K and V LDS-staged from contiguous 8KB tiles (coalesced
// gload_lds, XOR-swizzled both sides), one step ahead, no over-staging.
// Every LDS-read block is SGB/lgkmcnt(0)/SGB-fenced before its buffer is
// restaged and before its consuming MFMAs. LDS map: kbufs [0,32K) (wave
// w's kbuf == its OWN sO slot), vbufs [32K,64K), sM/sL at 64K.
__global__ __launch_bounds__(256, 2) void k_attn(const unsigned short* __restrict__ Qh,
                                                 const unsigned short* __restrict__ Kh,
                                                 const unsigned short* __restrict__ Vt,
                                                 unsigned short* __restrict__ ctx) {
  const int tid = threadIdx.x;
  const int lane = tid & 63;
  const int w = tid >> 6;  // split-K wave index, 0..3
  const int ql = lane & 31, hi = lane >> 5;
  const int xq = ql & 7;

  const int L = (int)blockIdx.x;          // 0..767
  const int W = (L & 7) * 96 + (L >> 3);  // XCD-chunked work id
  const int h = W >> 6;
  const int b = W & 63;

  __shared__ __align__(16) char smem[66560];
  char* kbuf = smem + w * 8192;           // own sO slot union
  char* vbuf = smem + 32768 + w * 8192;
  float* sO = (float*)smem;               // [4][64][32]
  float* sM = (float*)(smem + 65536);     // [4][32]
  float* sL = (float*)(smem + 66048);     // [4][32]

  const unsigned short* Khp = Kh + (size_t)h * SEQ * 64;
  const unsigned short* Qhp = Qh + (size_t)h * SEQ * 64;
  const unsigned short* Vtp = Vt + (size_t)h * SEQ * 64;  // tiled [64][64][64]
  // pre-swizzled staging source offset (shorts): row = lane>>3, chunk^row
  const int kLaneOff = (lane >> 3) * 64 + ((lane & 7) ^ (lane >> 3)) * 8;

  for (int ph = 0; ph < 2; ++ph) {
    const int qt = ph ? (127 - b) : b;
    const int qg = qt * 32 + ql;
    const int dt = qt >> 1;  // diagonal 64-tile
    bf8 qf[4];
    {
      const unsigned short* qp = Qhp + (size_t)qg * 64 + hi * 8;
      qf[0] = *reinterpret_cast<const bf8*>(qp);
      qf[1] = *reinterpret_cast<const bf8*>(qp + 16);
      qf[2] = *reinterpret_cast<const bf8*>(qp + 32);
      qf[3] = *reinterpret_cast<const bf8*>(qp + 48);
    }
    f32x16 o0 = {}, o1 = {};
    float m = -1e30f, l = 0.f;

    const int nt = (dt >= w) ? ((dt - w) >> 2) + 1 : 0;
    if (nt > 0) {
      STAGE8K(Khp, w, kbuf);
      STAGE8K(Vtp, w, vbuf);
      for (int i = 0; i < nt; ++i) {
        const int t = w + 4 * i;
        STEP64(t, (i + 1 < nt));
      }
    }
    __syncthreads();  // all staging consumed; buffers reusable as sO

    // ---- 4-way split-K merge via LDS (sO[w] == wave w's own kbuf) ----
#pragma unroll
    for (int r = 0; r < 16; ++r) {
      int dr = (r & 3) + 8 * (r >> 2) + 4 * hi;
      sO[w * 2048 + dr * 32 + ql] = o0[r];
      sO[w * 2048 + (32 + dr) * 32 + ql] = o1[r];
    }
    if (hi == 0) { sM[w * 32 + ql] = m; sL[w * 32 + ql] = l; }
    __syncthreads();
    {
      const int q = tid & 31;
      const int dblk = tid >> 5;  // 0..7, 8 d-values each
      float m0 = sM[q], m1 = sM[32 + q], m2 = sM[64 + q], m3 = sM[96 + q];
      float mn = fmaxf(fmaxf(m0, m1), fmaxf(m2, m3));
      float a0 = __builtin_amdgcn_exp2f(m0 - mn);
      float a1 = __builtin_amdgcn_exp2f(m1 - mn);
      float a2 = __builtin_amdgcn_exp2f(m2 - mn);
      float a3 = __builtin_amdgcn_exp2f(m3 - mn);
      float inv = 1.f / (a0 * sL[q] + a1 * sL[32 + q] + a2 * sL[64 + q] + a3 * sL[96 + q]);
      a0 *= inv; a1 *= inv; a2 *= inv; a3 *= inv;
      unsigned short* cp = ctx + (size_t)(qt * 32 + q) * DM + h * HD + dblk * 8;
#pragma unroll
      for (int j = 0; j < 8; j += 2) {
        int d = dblk * 8 + j;
        float v0 = sO[d * 32 + q] * a0 + sO[2048 + d * 32 + q] * a1 +
                   sO[4096 + d * 32 + q] * a2 + sO[6144 + d * 32 + q] * a3;
        float v1 = sO[(d + 1) * 32 + q] * a0 + sO[2048 + (d + 1) * 32 + q] * a1 +
                   sO[4096 + (d + 1) * 32 + q] * a2 + sO[6144 + (d + 1) * 32 + q] * a3;
        *reinterpret_cast<unsigned int*>(cp + j) = cvtpk(v0, v1);
      }
    }
    __syncthreads();  // merge reads done before phase-2 restage
  }
}

extern "C" void kernel_launch(void* const* d_in, const int* in_sizes, int n_in,
                              void* d_out, int out_size, void* d_ws, size_t ws_size,
                              hipStream_t stream) {
  const float* x  = (const float*)d_in[0];
  const float* Wq = (const float*)d_in[1];
  const float* Wk = (const float*)d_in[2];
  const float* Wv = (const float*)d_in[3];
  const float* Wo = (const float*)d_in[4];
  const float* bo = (const float*)d_in[5];

  unsigned short* xb = (unsigned short*)d_ws;
  unsigned short* wt = xb + (size_t)SEQ * DM;
  unsigned short* Qh = wt + (size_t)4 * DM * DM;
  unsigned short* Kh = Qh + (size_t)SEQ * DM;
  unsigned short* Vt = Kh + (size_t)SEQ * DM;
  unsigned short* cx = Vt + (size_t)SEQ * DM;

  const float qscale = 1.4426950408889634f / 8.0f;  // log2(e)/sqrt(HD)

  k_cvt<<<(SEQ * DM) / 1024, 256, 0, stream>>>(x, xb);
  k_tw<<<dim3(24, 24, 4), 256, 0, stream>>>(Wq, Wk, Wv, Wo, wt);
  dim3 gg(SEQ / 128, DM / 64);
  k_gemm<0><<<gg, 256, 0, stream>>>(xb, wt, Qh, nullptr, qscale);
  k_gemm<0><<<gg, 256, 0, stream>>>(xb, wt + (size_t)DM * DM, Kh, nullptr, 1.0f);
  k_gemm<1><<<gg, 256, 0, stream>>>(xb, wt + (size_t)2 * DM * DM, Vt, nullptr, 1.0f);
  k_attn<<<dim3(768), 256, 0, stream>>>(Qh, Kh, Vt, cx);
  k_gemm<2><<<gg, 256, 0, stream>>>(cx, wt + (size_t)3 * DM * DM, d_out, bo, 1.0f);
}

// Round 15
// 120.121 us; speedup vs baseline: 1.3581x; 1.0212x over previous
//
#include <hip/hip_runtime.h>
#include <stdint.h>

#define SEQ 4096
#define DM 768
#define NH 12
#define HD 64

typedef __attribute__((ext_vector_type(8))) short bf8;
typedef __attribute__((ext_vector_type(4))) float f4;
typedef __attribute__((ext_vector_type(16))) float f32x16;

static __device__ __forceinline__ f4 mfma_bf16(bf8 a, bf8 b, f4 c) {
  return __builtin_amdgcn_mfma_f32_16x16x32_bf16(a, b, c, 0, 0, 0);
}
static __device__ __forceinline__ f32x16 mfma32(bf8 a, bf8 b, f32x16 c) {
  return __builtin_amdgcn_mfma_f32_32x32x16_bf16(a, b, c, 0, 0, 0);
}

// RNE float->bf16 (bit pattern)
static __device__ __forceinline__ unsigned short f2bf(float f) {
  unsigned int u = __float_as_uint(f);
  u += 0x7FFFu + ((u >> 16) & 1u);
  return (unsigned short)(u >> 16);
}

// packed f32 pair -> bf16 pair (lo in low 16, hi in high 16)
static __device__ __forceinline__ unsigned int cvtpk(float lo, float hi) {
  unsigned int r;
  asm("v_cvt_pk_bf16_f32 %0, %1, %2" : "=v"(r) : "v"(lo), "v"(hi));
  return r;
}

static __device__ __forceinline__ void gload_lds16(const void* g, void* l) {
  __builtin_amdgcn_global_load_lds(
      (const __attribute__((address_space(1))) void*)g,
      (__attribute__((address_space(3))) void*)l, 16, 0, 0);
}

// ---- cast x (fp32) -> bf16 -----------------------------------------------
__global__ __launch_bounds__(256) void k_cvt(const float* __restrict__ x,
                                             unsigned short* __restrict__ xb) {
  int i = (blockIdx.x * 256 + threadIdx.x) * 4;
  float4 v = *reinterpret_cast<const float4*>(x + i);
  ushort4 o;
  o.x = f2bf(v.x); o.y = f2bf(v.y); o.z = f2bf(v.z); o.w = f2bf(v.w);
  *reinterpret_cast<ushort4*>(xb + i) = o;
}

// ---- transpose+cast weights: WT[z][n][k] = bf16(W[k][n]) -----------------
__global__ __launch_bounds__(256) void k_tw(const float* __restrict__ w0,
                                            const float* __restrict__ w1,
                                            const float* __restrict__ w2,
                                            const float* __restrict__ w3,
                                            unsigned short* __restrict__ wt) {
  const float* W = blockIdx.z == 0 ? w0 : blockIdx.z == 1 ? w1
                 : blockIdx.z == 2 ? w2 : w3;
  unsigned short* WT = wt + (size_t)blockIdx.z * DM * DM;
  __shared__ float t[32][33];
  int c0 = blockIdx.x * 32, r0 = blockIdx.y * 32;
  int lx = threadIdx.x & 31, ly = threadIdx.x >> 5;
#pragma unroll
  for (int rr = 0; rr < 32; rr += 8)
    t[ly + rr][lx] = W[(size_t)(r0 + ly + rr) * DM + c0 + lx];
  __syncthreads();
#pragma unroll
  for (int rr = 0; rr < 32; rr += 8)
    WT[(size_t)(c0 + ly + rr) * DM + r0 + lx] = f2bf(t[lx][ly + rr]);
}

// ---- bf16 MFMA GEMM, 128x128 tile, 4 waves (2x2), wave tile 64x64 --------
// MODE 3: fused QKV. Bt = [2304][768] (Wq^T|Wk^T|Wv^T). Routes by
//         zone=col/768 (block-uniform; 768%128==0): Q->per-head*qscale,
//         K->per-head, V->tiled [h][ktile][d][ks].
// MODE 2: out-proj, fp32 [row][768] + bias[col].
template <int MODE>
__global__ __launch_bounds__(256) void k_gemm2(const unsigned short* __restrict__ A,
                                               const unsigned short* __restrict__ Bt,
                                               unsigned short* __restrict__ Qh,
                                               unsigned short* __restrict__ Kh,
                                               unsigned short* __restrict__ Vtl,
                                               float* __restrict__ Cf,
                                               const float* __restrict__ bias,
                                               float qscale) {
  __shared__ unsigned short sA[128 * 32];
  __shared__ unsigned short sB[128 * 32];
  const int t = threadIdx.x, lane = t & 63, w = t >> 6;
  const int wr = w >> 1, wc = w & 1;
  const int c = lane & 15, g = lane >> 4;
  const int brow = blockIdx.x * 128, bcol = blockIdx.y * 128;
  f4 acc[4][4] = {};
  for (int k0 = 0; k0 < DM; k0 += 32) {
#pragma unroll
    for (int i = 0; i < 2; ++i) {
      int slot = w * 2 + i;
      int chunk = slot * 64 + lane;
      int row = chunk >> 2;
      int sl = (chunk & 3) ^ ((row >> 1) & 3);
      gload_lds16(A + (size_t)(brow + row) * DM + k0 + sl * 8, &sA[slot * 512]);
    }
#pragma unroll
    for (int i = 0; i < 2; ++i) {
      int slot = w * 2 + i;
      int chunk = slot * 64 + lane;
      int row = chunk >> 2;
      int sl = (chunk & 3) ^ ((row >> 1) & 3);
      gload_lds16(Bt + (size_t)(bcol + row) * DM + k0 + sl * 8, &sB[slot * 512]);
    }
    __syncthreads();
    bf8 af[4], bfr[4];
#pragma unroll
    for (int m = 0; m < 4; ++m) {
      int row = wr * 64 + m * 16 + c;
      int off = row * 64 + ((g * 16) ^ (((row >> 1) & 3) << 4));
      af[m] = *reinterpret_cast<const bf8*>(reinterpret_cast<const char*>(sA) + off);
    }
#pragma unroll
    for (int n = 0; n < 4; ++n) {
      int row = wc * 64 + n * 16 + c;
      int off = row * 64 + ((g * 16) ^ (((row >> 1) & 3) << 4));
      bfr[n] = *reinterpret_cast<const bf8*>(reinterpret_cast<const char*>(sB) + off);
    }
#pragma unroll
    for (int m = 0; m < 4; ++m)
#pragma unroll
      for (int n = 0; n < 4; ++n)
        acc[m][n] = mfma_bf16(af[m], bfr[n], acc[m][n]);
    __syncthreads();
  }
#pragma unroll
  for (int m = 0; m < 4; ++m) {
#pragma unroll
    for (int n = 0; n < 4; ++n) {
      int col = bcol + wc * 64 + n * 16 + c;
      int row0 = brow + wr * 64 + m * 16 + g * 4;
      if (MODE == 3) {
        int zone = col / 768;
        int ci = col - zone * 768;
        int h = ci >> 6, d = ci & 63;
        if (zone == 0) {
#pragma unroll
          for (int r = 0; r < 4; ++r)
            Qh[((size_t)h * SEQ + row0 + r) * 64 + d] = f2bf(acc[m][n][r] * qscale);
        } else if (zone == 1) {
#pragma unroll
          for (int r = 0; r < 4; ++r)
            Kh[((size_t)h * SEQ + row0 + r) * 64 + d] = f2bf(acc[m][n][r]);
        } else {
          ushort4 p;
          p.x = f2bf(acc[m][n][0]); p.y = f2bf(acc[m][n][1]);
          p.z = f2bf(acc[m][n][2]); p.w = f2bf(acc[m][n][3]);
          // row0 = k index; tile = row0>>6, ks = row0&63 (row0%4==0)
          *reinterpret_cast<ushort4*>(
              Vtl + ((((size_t)h * 64 + (row0 >> 6)) * 64 + d) * 64 + (row0 & 63))) = p;
        }
      } else {
#pragma unroll
        for (int r = 0; r < 4; ++r)
          Cf[(size_t)(row0 + r) * DM + col] = acc[m][n][r] + bias[col];
      }
    }
  }
}

// ---- attention helpers ----------------------------------------------------
#define PSWAP(a, b) asm volatile("v_permlane32_swap_b32 %0, %1" : "+v"(a), "+v"(b))
#define SGB() __builtin_amdgcn_sched_barrier(0)

// Stage a 64x64 bf16 tile (contiguous 8KB) into LDS, pre-swizzled source
// (chunk ^= row&7) so linear LDS dest + swizzled ds_read match (rule #21).
#define STAGE8K(srcbase, tile, dst) do {                                      \
    const unsigned short* s_ = (srcbase) + (size_t)(tile) * 4096 + kLaneOff;  \
    _Pragma("unroll")                                                         \
    for (int j_ = 0; j_ < 8; ++j_)                                            \
      gload_lds16(s_ + j_ * 512, (dst) + j_ * 1024);                          \
  } while (0)

// 16 P-values (one f32x16, already masked) -> exp -> two bf8 B-fragments.
#define PBUILD(sv, pfx, pfy) do {                                             \
    float p0_ = __builtin_amdgcn_exp2f(sv[0] - mn_);                          \
    float p1_ = __builtin_amdgcn_exp2f(sv[1] - mn_);                          \
    float p2_ = __builtin_amdgcn_exp2f(sv[2] - mn_);                          \
    float p3_ = __builtin_amdgcn_exp2f(sv[3] - mn_);                          \
    float p4_ = __builtin_amdgcn_exp2f(sv[4] - mn_);                          \
    float p5_ = __builtin_amdgcn_exp2f(sv[5] - mn_);                          \
    float p6_ = __builtin_amdgcn_exp2f(sv[6] - mn_);                          \
    float p7_ = __builtin_amdgcn_exp2f(sv[7] - mn_);                          \
    unsigned int wa0_ = cvtpk(p0_, p1_), wa1_ = cvtpk(p2_, p3_);              \
    unsigned int wb0_ = cvtpk(p4_, p5_), wb1_ = cvtpk(p6_, p7_);              \
    ls_ += ((p0_ + p1_) + (p2_ + p3_)) + ((p4_ + p5_) + (p6_ + p7_));         \
    float q0_ = __builtin_amdgcn_exp2f(sv[8] - mn_);                          \
    float q1_ = __builtin_amdgcn_exp2f(sv[9] - mn_);                          \
    float q2_ = __builtin_amdgcn_exp2f(sv[10] - mn_);                         \
    float q3_ = __builtin_amdgcn_exp2f(sv[11] - mn_);                         \
    float q4_ = __builtin_amdgcn_exp2f(sv[12] - mn_);                         \
    float q5_ = __builtin_amdgcn_exp2f(sv[13] - mn_);                         \
    float q6_ = __builtin_amdgcn_exp2f(sv[14] - mn_);                         \
    float q7_ = __builtin_amdgcn_exp2f(sv[15] - mn_);                         \
    unsigned int wc0_ = cvtpk(q0_, q1_), wc1_ = cvtpk(q2_, q3_);              \
    unsigned int wd0_ = cvtpk(q4_, q5_), wd1_ = cvtpk(q6_, q7_);              \
    ls_ += ((q0_ + q1_) + (q2_ + q3_)) + ((q4_ + q5_) + (q6_ + q7_));         \
    PSWAP(wa0_, wb0_);                                                        \
    PSWAP(wa1_, wb1_);                                                        \
    PSWAP(wc0_, wd0_);                                                        \
    PSWAP(wc1_, wd1_);                                                        \
    uint4 u0_ = {wa0_, wa1_, wb0_, wb1_};                                     \
    uint4 u1_ = {wc0_, wc1_, wd0_, wd1_};                                     \
    pfx = *reinterpret_cast<bf8*>(&u0_);                                      \
    pfy = *reinterpret_cast<bf8*>(&u1_);                                      \
  } while (0)

#define FMAX8(v, i0) fmaxf(fmaxf(fmaxf(v[i0], v[i0+1]), fmaxf(v[i0+2], v[i0+3])), \
                           fmaxf(fmaxf(v[i0+4], v[i0+5]), fmaxf(v[i0+6], v[i0+7])))

// Cross-half (lane i <-> i+32) reduce via permlane32_swap. The opaque asm
// copy forces 'cp' into a register DISTINCT from 'x' (R7 lesson).
#define XHALF_MAX(x) do {                                                     \
    float cp_ = (x);                                                          \
    asm volatile("" : "+v"(cp_));                                             \
    PSWAP((x), cp_);                                                          \
    (x) = fmaxf((x), cp_);                                                    \
  } while (0)
#define XHALF_ADD(x) do {                                                     \
    float cp_ = (x);                                                          \
    asm volatile("" : "+v"(cp_));                                             \
    PSWAP((x), cp_);                                                          \
    (x) = (x) + cp_;                                                          \
  } while (0)

// One KVBLK=64 step. Each buffer's ds_reads are fenced (SGB/lgkmcnt(0)/SGB)
// BEFORE its restage overwrites it, and before the MFMAs that consume them
// (rule #18). Defer-max (T13, THR=8 in log2 domain).
#define STEP64(t, stage_) do {                                                \
    asm volatile("s_waitcnt vmcnt(0)" ::: "memory");                          \
    SGB();                                                                    \
    const int x0_ = ((hi) ^ xq) << 4;                                         \
    const int x1_ = ((2 + hi) ^ xq) << 4;                                     \
    const int x2_ = ((4 + hi) ^ xq) << 4;                                     \
    const int x3_ = ((6 + hi) ^ xq) << 4;                                     \
    const char* kr0_ = kbuf + ql * 128;                                       \
    const char* kr1_ = kbuf + (32 + ql) * 128;                                \
    bf8 ka0_ = *(const bf8*)(kr0_ + x0_);                                     \
    bf8 kb0_ = *(const bf8*)(kr1_ + x0_);                                     \
    bf8 ka1_ = *(const bf8*)(kr0_ + x1_);                                     \
    bf8 kb1_ = *(const bf8*)(kr1_ + x1_);                                     \
    bf8 ka2_ = *(const bf8*)(kr0_ + x2_);                                     \
    bf8 kb2_ = *(const bf8*)(kr1_ + x2_);                                     \
    bf8 ka3_ = *(const bf8*)(kr0_ + x3_);                                     \
    bf8 kb3_ = *(const bf8*)(kr1_ + x3_);                                     \
    SGB();                                                                    \
    asm volatile("s_waitcnt lgkmcnt(0)" ::: "memory");                        \
    SGB();                                                                    \
    if (stage_) STAGE8K(Khp, (t) + 4, kbuf);                                  \
    f32x16 s0_ = {}, s1_ = {};                                                \
    __builtin_amdgcn_s_setprio(1);                                            \
    s0_ = mfma32(ka0_, qf[0], s0_);  s1_ = mfma32(kb0_, qf[0], s1_);          \
    s0_ = mfma32(ka1_, qf[1], s0_);  s1_ = mfma32(kb1_, qf[1], s1_);          \
    s0_ = mfma32(ka2_, qf[2], s0_);  s1_ = mfma32(kb2_, qf[2], s1_);          \
    s0_ = mfma32(ka3_, qf[3], s0_);  s1_ = mfma32(kb3_, qf[3], s1_);          \
    __builtin_amdgcn_s_setprio(0);                                            \
    if ((t) == dt) {                                                          \
      _Pragma("unroll")                                                       \
      for (int r_ = 0; r_ < 16; ++r_) {                                       \
        int kr_ = (t) * 64 + (r_ & 3) + 8 * (r_ >> 2) + 4 * hi;               \
        s0_[r_] = (kr_ > qg) ? -1e30f : s0_[r_];                              \
        s1_[r_] = (kr_ + 32 > qg) ? -1e30f : s1_[r_];                         \
      }                                                                       \
    }                                                                         \
    float tm_ = fmaxf(fmaxf(FMAX8(s0_, 0), FMAX8(s0_, 8)),                    \
                      fmaxf(FMAX8(s1_, 0), FMAX8(s1_, 8)));                   \
    XHALF_MAX(tm_);                                                           \
    float mn_, al_;                                                           \
    if (__all(tm_ <= m + 8.f)) {                                              \
      mn_ = m;                                                                \
      al_ = 1.0f;                                                             \
    } else {                                                                  \
      mn_ = fmaxf(m, tm_);                                                    \
      al_ = __builtin_amdgcn_exp2f(m - mn_);                                  \
      m = mn_;                                                                \
      _Pragma("unroll")                                                       \
      for (int r_ = 0; r_ < 16; ++r_) { o0[r_] *= al_; o1[r_] *= al_; }       \
    }                                                                         \
    float ls_ = 0.f;                                                          \
    bf8 pfA0_, pfA1_, pfB0_, pfB1_;                                           \
    PBUILD(s0_, pfA0_, pfA1_);                                                \
    PBUILD(s1_, pfB0_, pfB1_);                                                \
    XHALF_ADD(ls_);                                                           \
    l = l * al_ + ls_;                                                        \
    const char* vr0_ = vbuf + ql * 128;                                       \
    const char* vr1_ = vbuf + (32 + ql) * 128;                                \
    bf8 va0_ = *(const bf8*)(vr0_ + x0_);                                     \
    bf8 va1_ = *(const bf8*)(vr0_ + x1_);                                     \
    bf8 va2_ = *(const bf8*)(vr0_ + x2_);                                     \
    bf8 va3_ = *(const bf8*)(vr0_ + x3_);                                     \
    bf8 vb0_ = *(const bf8*)(vr1_ + x0_);                                     \
    bf8 vb1_ = *(const bf8*)(vr1_ + x1_);                                     \
    bf8 vb2_ = *(const bf8*)(vr1_ + x2_);                                     \
    bf8 vb3_ = *(const bf8*)(vr1_ + x3_);                                     \
    SGB();                                                                    \
    asm volatile("s_waitcnt lgkmcnt(0)" ::: "memory");                        \
    SGB();                                                                    \
    if (stage_) STAGE8K(Vtp, (t) + 4, vbuf);                                  \
    __builtin_amdgcn_s_setprio(1);                                            \
    o0 = mfma32(va0_, pfA0_, o0);                                             \
    o0 = mfma32(va1_, pfA1_, o0);                                             \
    o0 = mfma32(va2_, pfB0_, o0);                                             \
    o0 = mfma32(va3_, pfB1_, o0);                                             \
    o1 = mfma32(vb0_, pfA0_, o1);                                             \
    o1 = mfma32(vb1_, pfA1_, o1);                                             \
    o1 = mfma32(vb2_, pfB0_, o1);                                             \
    o1 = mfma32(vb3_, pfB1_, o1);                                             \
    __builtin_amdgcn_s_setprio(0);                                            \
  } while (0)

// ---- causal flash attention: paired q-tiles + split-K x4 + XCD chunking --
// KVBLK=64. K and V LDS-staged from contiguous 8KB tiles (coalesced
// gload_lds, XOR-swizzled both sides), one step ahead, no over-staging.
// Every LDS-read block is SGB/lgkmcnt(0)/SGB-fenced before its buffer is
// restaged and before its consuming MFMAs. LDS map: kbufs [0,32K) (wave
// w's kbuf == its OWN sO slot), vbufs [32K,64K), sM/sL at 64K.
__global__ __launch_bounds__(256, 2) void k_attn(const unsigned short* __restrict__ Qh,
                                                 const unsigned short* __restrict__ Kh,
                                                 const unsigned short* __restrict__ Vt,
                                                 unsigned short* __restrict__ ctx) {
  const int tid = threadIdx.x;
  const int lane = tid & 63;
  const int w = tid >> 6;  // split-K wave index, 0..3
  const int ql = lane & 31, hi = lane >> 5;
  const int xq = ql & 7;

  const int L = (int)blockIdx.x;          // 0..767
  const int W = (L & 7) * 96 + (L >> 3);  // XCD-chunked work id
  const int h = W >> 6;
  const int b = W & 63;

  __shared__ __align__(16) char smem[66560];
  char* kbuf = smem + w * 8192;           // own sO slot union
  char* vbuf = smem + 32768 + w * 8192;
  float* sO = (float*)smem;               // [4][64][32]
  float* sM = (float*)(smem + 65536);     // [4][32]
  float* sL = (float*)(smem + 66048);     // [4][32]

  const unsigned short* Khp = Kh + (size_t)h * SEQ * 64;
  const unsigned short* Qhp = Qh + (size_t)h * SEQ * 64;
  const unsigned short* Vtp = Vt + (size_t)h * SEQ * 64;  // tiled [64][64][64]
  // pre-swizzled staging source offset (shorts): row = lane>>3, chunk^row
  const int kLaneOff = (lane >> 3) * 64 + ((lane & 7) ^ (lane >> 3)) * 8;

  for (int ph = 0; ph < 2; ++ph) {
    const int qt = ph ? (127 - b) : b;
    const int qg = qt * 32 + ql;
    const int dt = qt >> 1;  // diagonal 64-tile
    bf8 qf[4];
    {
      const unsigned short* qp = Qhp + (size_t)qg * 64 + hi * 8;
      qf[0] = *reinterpret_cast<const bf8*>(qp);
      qf[1] = *reinterpret_cast<const bf8*>(qp + 16);
      qf[2] = *reinterpret_cast<const bf8*>(qp + 32);
      qf[3] = *reinterpret_cast<const bf8*>(qp + 48);
    }
    f32x16 o0 = {}, o1 = {};
    float m = -1e30f, l = 0.f;

    const int nt = (dt >= w) ? ((dt - w) >> 2) + 1 : 0;
    if (nt > 0) {
      STAGE8K(Khp, w, kbuf);
      STAGE8K(Vtp, w, vbuf);
      for (int i = 0; i < nt; ++i) {
        const int t = w + 4 * i;
        STEP64(t, (i + 1 < nt));
      }
    }
    __syncthreads();  // all staging consumed; buffers reusable as sO

    // ---- 4-way split-K merge via LDS (sO[w] == wave w's own kbuf) ----
#pragma unroll
    for (int r = 0; r < 16; ++r) {
      int dr = (r & 3) + 8 * (r >> 2) + 4 * hi;
      sO[w * 2048 + dr * 32 + ql] = o0[r];
      sO[w * 2048 + (32 + dr) * 32 + ql] = o1[r];
    }
    if (hi == 0) { sM[w * 32 + ql] = m; sL[w * 32 + ql] = l; }
    __syncthreads();
    {
      const int q = tid & 31;
      const int dblk = tid >> 5;  // 0..7, 8 d-values each
      float m0 = sM[q], m1 = sM[32 + q], m2 = sM[64 + q], m3 = sM[96 + q];
      float mn = fmaxf(fmaxf(m0, m1), fmaxf(m2, m3));
      float a0 = __builtin_amdgcn_exp2f(m0 - mn);
      float a1 = __builtin_amdgcn_exp2f(m1 - mn);
      float a2 = __builtin_amdgcn_exp2f(m2 - mn);
      float a3 = __builtin_amdgcn_exp2f(m3 - mn);
      float inv = 1.f / (a0 * sL[q] + a1 * sL[32 + q] + a2 * sL[64 + q] + a3 * sL[96 + q]);
      a0 *= inv; a1 *= inv; a2 *= inv; a3 *= inv;
      unsigned short* cp = ctx + (size_t)(qt * 32 + q) * DM + h * HD + dblk * 8;
#pragma unroll
      for (int j = 0; j < 8; j += 2) {
        int d = dblk * 8 + j;
        float v0 = sO[d * 32 + q] * a0 + sO[2048 + d * 32 + q] * a1 +
                   sO[4096 + d * 32 + q] * a2 + sO[6144 + d * 32 + q] * a3;
        float v1 = sO[(d + 1) * 32 + q] * a0 + sO[2048 + (d + 1) * 32 + q] * a1 +
                   sO[4096 + (d + 1) * 32 + q] * a2 + sO[6144 + (d + 1) * 32 + q] * a3;
        *reinterpret_cast<unsigned int*>(cp + j) = cvtpk(v0, v1);
      }
    }
    __syncthreads();  // merge reads done before phase-2 restage
  }
}

extern "C" void kernel_launch(void* const* d_in, const int* in_sizes, int n_in,
                              void* d_out, int out_size, void* d_ws, size_t ws_size,
                              hipStream_t stream) {
  const float* x  = (const float*)d_in[0];
  const float* Wq = (const float*)d_in[1];
  const float* Wk = (const float*)d_in[2];
  const float* Wv = (const float*)d_in[3];
  const float* Wo = (const float*)d_in[4];
  const float* bo = (const float*)d_in[5];

  unsigned short* xb = (unsigned short*)d_ws;
  unsigned short* wt = xb + (size_t)SEQ * DM;
  unsigned short* Qh = wt + (size_t)4 * DM * DM;
  unsigned short* Kh = Qh + (size_t)SEQ * DM;
  unsigned short* Vt = Kh + (size_t)SEQ * DM;
  unsigned short* cx = Vt + (size_t)SEQ * DM;

  const float qscale = 1.4426950408889634f / 8.0f;  // log2(e)/sqrt(HD)

  k_cvt<<<(SEQ * DM) / 1024, 256, 0, stream>>>(x, xb);
  k_tw<<<dim3(24, 24, 4), 256, 0, stream>>>(Wq, Wk, Wv, Wo, wt);
  // fused QKV GEMM over Bt=[2304][768] (wt holds Wq^T|Wk^T|Wv^T contiguous)
  k_gemm2<3><<<dim3(SEQ / 128, 2304 / 128), 256, 0, stream>>>(
      xb, wt, Qh, Kh, Vt, nullptr, nullptr, qscale);
  k_attn<<<dim3(768), 256, 0, stream>>>(Qh, Kh, Vt, cx);
  k_gemm2<2><<<dim3(SEQ / 128, DM / 128), 256, 0, stream>>>(
      cx, wt + (size_t)3 * DM * DM, nullptr, nullptr, nullptr,
      (float*)d_out, bo, 1.0f);
}